// Round 2
// baseline (1288.316 us; speedup 1.0000x reference)
//
#include <hip/hip_runtime.h>
#include <hip/hip_bf16.h>
#include <math.h>

// Problem constants (fixed by the reference)
#define B_   8
#define N_   4096
#define C_   256
#define NH_  8
#define D_   32
#define S_   256      // (64/4)*(64/4)
#define HH_  64       // H = W = 64

// ---------------------------------------------------------------------------
// Gather 4x4xC patches into P[b*S+s][c*16 + p*4 + q]  (rows 2048, cols 4096)
// so the subsample conv becomes GEMM: src = P @ sr_w_flat^T  (sr_w is OIHW).
// ---------------------------------------------------------------------------
__global__ __launch_bounds__(256) void gather_kernel(const float* __restrict__ x,
                                                     float* __restrict__ P) {
    int bs = blockIdx.x;                 // b*256 + s
    int b = bs >> 8, s = bs & 255;
    int i = s >> 4, j = s & 15;
    int c = threadIdx.x;
    const float* xb = x + (size_t)b * N_ * C_;
    float vals[16];
#pragma unroll
    for (int pq = 0; pq < 16; ++pq) {
        int p = pq >> 2, q = pq & 3;
        int n = (i * 4 + p) * HH_ + (j * 4 + q);
        vals[pq] = xb[(size_t)n * C_ + c];   // coalesced across c
    }
    float4* dst = (float4*)(P + (size_t)bs * 4096 + c * 16);
#pragma unroll
    for (int t = 0; t < 4; ++t)
        dst[t] = make_float4(vals[4*t], vals[4*t+1], vals[4*t+2], vals[4*t+3]);
}

// ---------------------------------------------------------------------------
// C[m,n] = act( (accum ? C[m,n] : 0) + sum_k A[m,k]*W[n,k] + bias[n] )
// A: [M, lda] row-major, W: [N-ish, ldw] row-major (NT gemm). ldc == Nw.
// act: 0 none, 1 elu(x)+1, 2 relu.  Tile 64x64, BK=16, 4x4 per thread.
// M, N assumed multiples of 64; K multiple of 16 (true for all calls).
// ---------------------------------------------------------------------------
__global__ __launch_bounds__(256) void gemm_nt(const float* __restrict__ A, int lda,
                                               const float* __restrict__ W, int ldw,
                                               const float* __restrict__ bias,
                                               float* __restrict__ Cmat, int Nw, int K,
                                               int act, int accum) {
    __shared__ float As[16][65];
    __shared__ float Ws[16][65];
    const int bm = blockIdx.x * 64;
    const int bn = blockIdx.y * 64;
    const int tid = threadIdx.x;
    const int tx = tid & 15, ty = tid >> 4;
    const int lr = tid >> 2, lq = (tid & 3) * 4;   // load: row lr, k-quad lq
    float acc[4][4] = {};
    for (int k0 = 0; k0 < K; k0 += 16) {
        float4 av = *(const float4*)(A + (size_t)(bm + lr) * lda + k0 + lq);
        float4 wv = *(const float4*)(W + (size_t)(bn + lr) * ldw + k0 + lq);
        As[lq+0][lr] = av.x; As[lq+1][lr] = av.y; As[lq+2][lr] = av.z; As[lq+3][lr] = av.w;
        Ws[lq+0][lr] = wv.x; Ws[lq+1][lr] = wv.y; Ws[lq+2][lr] = wv.z; Ws[lq+3][lr] = wv.w;
        __syncthreads();
#pragma unroll
        for (int kk = 0; kk < 16; ++kk) {
            float a[4], bb[4];
#pragma unroll
            for (int ii = 0; ii < 4; ++ii) a[ii] = As[kk][ty*4+ii];
#pragma unroll
            for (int jj = 0; jj < 4; ++jj) bb[jj] = Ws[kk][tx*4+jj];
#pragma unroll
            for (int ii = 0; ii < 4; ++ii)
#pragma unroll
                for (int jj = 0; jj < 4; ++jj)
                    acc[ii][jj] = fmaf(a[ii], bb[jj], acc[ii][jj]);
        }
        __syncthreads();
    }
#pragma unroll
    for (int ii = 0; ii < 4; ++ii) {
        int row = bm + ty*4 + ii;
#pragma unroll
        for (int jj = 0; jj < 4; ++jj) {
            int col = bn + tx*4 + jj;
            float v = acc[ii][jj];
            if (bias) v += bias[col];
            size_t idx = (size_t)row * Nw + col;
            if (accum) v += Cmat[idx];
            if (act == 1) v = v > 0.f ? v + 1.f : __expf(v);   // elu(x)+1
            else if (act == 2) v = fmaxf(v, 0.f);
            Cmat[idx] = v;
        }
    }
}

// ---------------------------------------------------------------------------
// LayerNorm over last dim (C=256), one block per row; optional residual add.
// Safe to run in place (each thread reads its element before any write).
// ---------------------------------------------------------------------------
__global__ __launch_bounds__(256) void ln_kernel(const float* __restrict__ in,
                                                 const float* __restrict__ g,
                                                 const float* __restrict__ bvec,
                                                 const float* __restrict__ residual,
                                                 float* __restrict__ out) {
    int row = blockIdx.x;
    int tid = threadIdx.x;
    float xv = in[(size_t)row * C_ + tid];
    __shared__ float r1[256], r2[256];
    r1[tid] = xv; r2[tid] = xv * xv;
    __syncthreads();
    for (int off = 128; off > 0; off >>= 1) {
        if (tid < off) { r1[tid] += r1[tid+off]; r2[tid] += r2[tid+off]; }
        __syncthreads();
    }
    float mean = r1[0] * (1.f / C_);
    float var  = r2[0] * (1.f / C_) - mean * mean;
    float y = (xv - mean) * rsqrtf(var + 1e-5f) * g[tid] + bvec[tid];
    if (residual) y += residual[(size_t)row * C_ + tid];
    out[(size_t)row * C_ + tid] = y;
}

// ---------------------------------------------------------------------------
// Per (b,h): KV[d][v] = sum_s K[b,s,h,d]*V[b,s,h,v];  Ksum[d] = sum_s K[b,s,h,d]
// (the reference's /S on V and *S on msg cancel; Z uses unscaled Ksum)
// ---------------------------------------------------------------------------
__global__ __launch_bounds__(256) void kv_kernel(const float* __restrict__ Kb,
                                                 const float* __restrict__ Vb,
                                                 float* __restrict__ KV,
                                                 float* __restrict__ Ksum) {
    int bh = blockIdx.x;                 // b*NH + h
    int b = bh >> 3, h = bh & 7;
    const float* Kp = Kb + (size_t)b * S_ * C_ + h * D_;
    const float* Vp = Vb + (size_t)b * S_ * C_ + h * D_;
    int tid = threadIdx.x;
    __shared__ float Ks[8][32], Vs[8][32];
    int d = tid >> 3, vq = tid & 7;      // thread computes KV[d][vq*4 .. vq*4+3]
    int ls = tid >> 5, lc = tid & 31;    // loader: 8 s-rows x 32 dims
    float acc[4] = {0.f, 0.f, 0.f, 0.f};
    float ks = 0.f;
    for (int s0 = 0; s0 < S_; s0 += 8) {
        __syncthreads();
        Ks[ls][lc] = Kp[(size_t)(s0 + ls) * C_ + lc];
        Vs[ls][lc] = Vp[(size_t)(s0 + ls) * C_ + lc];
        __syncthreads();
#pragma unroll
        for (int ss = 0; ss < 8; ++ss) {
            float kd = Ks[ss][d];
            if (vq == 0) ks += kd;
#pragma unroll
            for (int jj = 0; jj < 4; ++jj)
                acc[jj] += kd * Vs[ss][vq*4 + jj];
        }
    }
    float* kvout = KV + ((size_t)bh * 32 + d) * 32 + vq * 4;
#pragma unroll
    for (int jj = 0; jj < 4; ++jj) kvout[jj] = acc[jj];
    if (vq == 0) Ksum[bh * 32 + d] = ks;
}

// ---------------------------------------------------------------------------
// msg[row, h*32+v] = (sum_d Q[row,h,d]*KV[b,h,d,v]) / (sum_d Q[row,h,d]*Ksum[b,h,d] + eps)
// ---------------------------------------------------------------------------
__global__ __launch_bounds__(256) void msg_kernel(const float* __restrict__ Q,
                                                  const float* __restrict__ KV,
                                                  const float* __restrict__ Ksum,
                                                  float* __restrict__ out) {
    int row = blockIdx.x;                // b*N + l
    int b = row >> 12;                   // N = 4096
    int tid = threadIdx.x;
    __shared__ float Qs[256];
    Qs[tid] = Q[(size_t)row * C_ + tid];
    __syncthreads();
    int h = tid >> 5, v = tid & 31;
    const float* kvp = KV + (size_t)(b * NH_ + h) * 32 * 32;
    const float* ksp = Ksum + (b * NH_ + h) * 32;
    float z = 0.f, m = 0.f;
#pragma unroll
    for (int d = 0; d < 32; ++d) {
        float qd = Qs[h * 32 + d];
        z += qd * ksp[d];
        m += qd * kvp[d * 32 + v];
    }
    out[(size_t)row * C_ + tid] = m / (z + 1e-6f);
}

// ---------------------------------------------------------------------------
extern "C" void kernel_launch(void* const* d_in, const int* in_sizes, int n_in,
                              void* d_out, int out_size, void* d_ws, size_t ws_size,
                              hipStream_t stream) {
    const float* x      = (const float*)d_in[0];
    const float* sr_w   = (const float*)d_in[1];   // [256,256,4,4] OIHW == [256,4096]
    const float* sr_b   = (const float*)d_in[2];
    const float* norm_g = (const float*)d_in[3];
    const float* norm_b = (const float*)d_in[4];
    const float* wq     = (const float*)d_in[5];
    const float* wk     = (const float*)d_in[6];
    const float* wv     = (const float*)d_in[7];
    const float* wm     = (const float*)d_in[8];
    const float* w1     = (const float*)d_in[9];   // [512,512]
    const float* w2     = (const float*)d_in[10];  // [256,512]
    const float* n1g    = (const float*)d_in[11];
    const float* n1b    = (const float*)d_in[12];
    const float* n2g    = (const float*)d_in[13];
    const float* n2b    = (const float*)d_in[14];
    float* out = (float*)d_out;

    float* ws = (float*)d_ws;
    size_t off = 0;
    auto alloc = [&](size_t n) { float* p = ws + off; off += (n + 63) & ~63ull; return p; };
    float* P    = alloc(2048ull * 4096);   // patches; later reused as `merged`
    float* src  = alloc(2048ull * 256);
    float* kbuf = alloc(2048ull * 256);
    float* vbuf = alloc(2048ull * 256);
    float* qbuf = alloc(32768ull * 256);   // later reused as `msgn`
    float* msg  = alloc(32768ull * 256);   // later reused as `h2`
    float* h1   = alloc(32768ull * 512);
    float* KV   = alloc(64ull * 32 * 32);
    float* Ksum = alloc(64ull * 32);
    float* merged = P;
    float* msgn   = qbuf;
    float* h2     = msg;

    // 1. patch gather
    gather_kernel<<<2048, 256, 0, stream>>>(x, P);
    // 2. subsample conv as GEMM (+bias), then LN in place
    { dim3 g(2048/64, 256/64);
      gemm_nt<<<g, 256, 0, stream>>>(P, 4096, sr_w, 4096, sr_b, src, 256, 4096, 0, 0); }
    ln_kernel<<<2048, 256, 0, stream>>>(src, norm_g, norm_b, nullptr, src);
    // 3. K/V projections (K with elu+1), Q projection (elu+1)
    { dim3 g(2048/64, 256/64);
      gemm_nt<<<g, 256, 0, stream>>>(src, 256, wk, 256, nullptr, kbuf, 256, 256, 1, 0); }
    { dim3 g(2048/64, 256/64);
      gemm_nt<<<g, 256, 0, stream>>>(src, 256, wv, 256, nullptr, vbuf, 256, 256, 0, 0); }
    { dim3 g(32768/64, 256/64);
      gemm_nt<<<g, 256, 0, stream>>>(x, 256, wq, 256, nullptr, qbuf, 256, 256, 1, 0); }
    // 4. linear attention
    kv_kernel<<<64, 256, 0, stream>>>(kbuf, vbuf, KV, Ksum);
    msg_kernel<<<32768, 256, 0, stream>>>(qbuf, KV, Ksum, msg);
    // 5. merge proj + LN(norm1)
    { dim3 g(32768/64, 256/64);
      gemm_nt<<<g, 256, 0, stream>>>(msg, 256, wm, 256, nullptr, merged, 256, 256, 0, 0); }
    ln_kernel<<<32768, 256, 0, stream>>>(merged, n1g, n1b, nullptr, msgn);
    // 6. concat-MLP without materializing concat: two GEMMs into h1 (2nd accum+relu)
    { dim3 g(32768/64, 512/64);
      gemm_nt<<<g, 256, 0, stream>>>(x, 256, w1, 512, nullptr, h1, 512, 256, 0, 0); }
    { dim3 g(32768/64, 512/64);
      gemm_nt<<<g, 256, 0, stream>>>(msgn, 256, w1 + 256, 512, nullptr, h1, 512, 256, 2, 1); }
    { dim3 g(32768/64, 256/64);
      gemm_nt<<<g, 256, 0, stream>>>(h1, 512, w2, 512, nullptr, h2, 256, 512, 0, 0); }
    // 7. LN(norm2) + residual -> out
    ln_kernel<<<32768, 256, 0, stream>>>(h2, n2g, n2b, x, out);
}

// Round 4
// 403.412 us; speedup vs baseline: 3.1935x; 3.1935x over previous
//
#include <hip/hip_runtime.h>
#include <hip/hip_bf16.h>
#include <math.h>

// Problem constants (fixed by the reference)
#define B_   8
#define N_   4096
#define C_   256
#define NH_  8
#define D_   32
#define S_   256      // (64/4)*(64/4)
#define HH_  64       // H = W = 64

#define BM 128
#define BN 128
#define BK 32

typedef __bf16 bf16x8 __attribute__((ext_vector_type(8)));
typedef float f32x4 __attribute__((ext_vector_type(4)));

__device__ inline ushort f2b(float f) {
    __hip_bfloat16 h = __float2bfloat16(f);
    return *reinterpret_cast<ushort*>(&h);
}

__device__ inline void gload16(const void* g, void* l) {
    __builtin_amdgcn_global_load_lds(
        (const __attribute__((address_space(1))) unsigned int*)g,
        (__attribute__((address_space(3))) unsigned int*)l, 16, 0, 0);
}

// ---------------------------------------------------------------------------
// Batched fp32 -> bf16 weight cast (one launch for all 7 weight tensors)
// ---------------------------------------------------------------------------
#define NSEG 7
struct CastArgs {
    const float* s[NSEG];
    ushort*      d[NSEG];
    int          n4[NSEG];   // quads per segment
    int          total4;
};
__global__ __launch_bounds__(256) void cast_w_kernel(CastArgs a) {
    int idx = blockIdx.x * 256 + threadIdx.x;
    if (idx >= a.total4) return;
    int i = idx, s = 0;
    while (i >= a.n4[s]) { i -= a.n4[s]; ++s; }
    float4 f = ((const float4*)a.s[s])[i];
    ushort4 o;
    o.x = f2b(f.x); o.y = f2b(f.y); o.z = f2b(f.z); o.w = f2b(f.w);
    ((ushort4*)a.d[s])[i] = o;
}

// ---------------------------------------------------------------------------
// Gather 4x4xC patches -> P16[b*S+s][c*16+p*4+q] (bf16) AND write bf16 x into
// cat[:, 0:256] (cat is [32768][512] bf16, second half filled by norm1 later).
// ---------------------------------------------------------------------------
__global__ __launch_bounds__(256) void gather_kernel(const float* __restrict__ x,
                                                     ushort* __restrict__ P,
                                                     ushort* __restrict__ cat) {
    int bs = blockIdx.x;                 // b*256 + s
    int b = bs >> 8, s = bs & 255;
    int i = s >> 4, j = s & 15;
    int c = threadIdx.x;
    const float* xb = x + (size_t)b * N_ * C_;
    ushort u[16];
#pragma unroll
    for (int pq = 0; pq < 16; ++pq) {
        int p = pq >> 2, q = pq & 3;
        int n = (i * 4 + p) * HH_ + (j * 4 + q);
        float f = xb[(size_t)n * C_ + c];        // coalesced across c
        u[pq] = f2b(f);
        cat[((size_t)(b * N_ + n)) * 512 + c] = u[pq];   // coalesced across c
    }
    ushort* dst = P + (size_t)bs * 4096 + c * 16;
    ((uint4*)dst)[0] = *(uint4*)&u[0];
    ((uint4*)dst)[1] = *(uint4*)&u[8];
}

// ---------------------------------------------------------------------------
// bf16 MFMA GEMM (NT): C[m,n] = act( sum_k A[m,k] * W[n,k] )
// A [M][lda] bf16 row-major, W [N][ldw] bf16 row-major.
// 128x128 tile, BK=32, 4 waves, 4x4 16x16x32 fragments per wave.
// blockIdx.z = split-K slice (Kchunk each), writes Cf + z*spstride.
// act: 0 none, 1 elu(x)+1, 2 relu.  Output: Cb (bf16) if non-null else Cf.
// ---------------------------------------------------------------------------
__global__ __launch_bounds__(256) void gemm_bf16(
    const ushort* __restrict__ A, int lda,
    const ushort* __restrict__ W, int ldw,
    float* __restrict__ Cf, ushort* __restrict__ Cb, int ldc,
    int Kchunk, int act, long spstride)
{
    __shared__ ushort As[BM * BK];   // 8 KB, row-major [128][32]
    __shared__ ushort Bs[BN * BK];   // 8 KB
    const int t = threadIdx.x;
    const int lane = t & 63;
    const int w = t >> 6;
    const int wr = w >> 1, wc = w & 1;           // wave -> 64x64 quadrant
    const int fr = lane & 15, fq = lane >> 4;    // fragment row / k-group
    const int bm = blockIdx.x * BM, bn = blockIdx.y * BN;
    const long koff = (long)blockIdx.z * Kchunk;

    f32x4 acc[4][4] = {};

    const ushort* Ag = A + (size_t)bm * lda + koff;
    const ushort* Wg = W + (size_t)bn * ldw + koff;
    char* AsB = (char*)As;
    char* BsB = (char*)Bs;
    const int wuni = (t & ~63) * 16;             // wave-uniform LDS byte base

    for (int k0 = 0; k0 < Kchunk; k0 += BK) {
        // stage A,B tiles (8 KB each): 2 x 256 chunks of 16 B per tile
#pragma unroll
        for (int i = 0; i < 2; ++i) {
            int c = i * 256 + t;
            int row = c >> 2, kb = (c & 3) * 8;
            gload16(Ag + (size_t)row * lda + k0 + kb, AsB + i * 4096 + wuni);
            gload16(Wg + (size_t)row * ldw + k0 + kb, BsB + i * 4096 + wuni);
        }
        __syncthreads();   // compiler drains vmcnt(0) before barrier

        bf16x8 af[4], bv[4];
#pragma unroll
        for (int m = 0; m < 4; ++m)
            af[m] = *(const bf16x8*)&As[(wr * 64 + m * 16 + fr) * BK + fq * 8];
#pragma unroll
        for (int n = 0; n < 4; ++n)
            bv[n] = *(const bf16x8*)&Bs[(wc * 64 + n * 16 + fr) * BK + fq * 8];
#pragma unroll
        for (int m = 0; m < 4; ++m)
#pragma unroll
            for (int n = 0; n < 4; ++n)
                acc[m][n] = __builtin_amdgcn_mfma_f32_16x16x32_bf16(
                    af[m], bv[n], acc[m][n], 0, 0, 0);
        __syncthreads();
    }

    float* Cfz = Cf ? Cf + (size_t)blockIdx.z * spstride : nullptr;
#pragma unroll
    for (int m = 0; m < 4; ++m) {
#pragma unroll
        for (int n = 0; n < 4; ++n) {
            int col = bn + wc * 64 + n * 16 + fr;
#pragma unroll
            for (int i = 0; i < 4; ++i) {
                int row = bm + wr * 64 + m * 16 + fq * 4 + i;
                float v = acc[m][n][i];
                if (act == 1) v = v > 0.f ? v + 1.f : __expf(v);   // elu(x)+1
                else if (act == 2) v = fmaxf(v, 0.f);
                if (Cb) Cb[(size_t)row * ldc + col] = f2b(v);
                else    Cfz[(size_t)row * ldc + col] = v;
            }
        }
    }
}

// ---------------------------------------------------------------------------
// Sum 8 split-K partials + conv bias, then LayerNorm -> bf16 src
// ---------------------------------------------------------------------------
__global__ __launch_bounds__(256) void ln_reduce_kernel(
    const float* __restrict__ part,     // [8][2048][256]
    const float* __restrict__ bias,
    const float* __restrict__ g, const float* __restrict__ bvec,
    ushort* __restrict__ outb)
{
    int row = blockIdx.x, c = threadIdx.x;
    float v = bias[c];
#pragma unroll
    for (int s = 0; s < 8; ++s)
        v += part[(size_t)s * 2048 * 256 + (size_t)row * 256 + c];
    __shared__ float r1[256], r2[256];
    r1[c] = v; r2[c] = v * v;
    __syncthreads();
    for (int off = 128; off > 0; off >>= 1) {
        if (c < off) { r1[c] += r1[c + off]; r2[c] += r2[c + off]; }
        __syncthreads();
    }
    float mean = r1[0] * (1.f / C_);
    float var  = r2[0] * (1.f / C_) - mean * mean;
    float y = (v - mean) * rsqrtf(var + 1e-5f) * g[c] + bvec[c];
    outb[(size_t)row * C_ + c] = f2b(y);
}

// ---------------------------------------------------------------------------
// General LayerNorm over C=256. Input fp32 [rows][256]. Optional residual.
// Output: fp32 (outf) or bf16 (outb, leading dim ldout).
// ---------------------------------------------------------------------------
__global__ __launch_bounds__(256) void ln_kernel(
    const float* __restrict__ in,
    const float* __restrict__ g, const float* __restrict__ bvec,
    const float* __restrict__ residual,
    float* __restrict__ outf, ushort* __restrict__ outb, int ldout)
{
    int row = blockIdx.x, c = threadIdx.x;
    float xv = in[(size_t)row * C_ + c];
    __shared__ float r1[256], r2[256];
    r1[c] = xv; r2[c] = xv * xv;
    __syncthreads();
    for (int off = 128; off > 0; off >>= 1) {
        if (c < off) { r1[c] += r1[c + off]; r2[c] += r2[c + off]; }
        __syncthreads();
    }
    float mean = r1[0] * (1.f / C_);
    float var  = r2[0] * (1.f / C_) - mean * mean;
    float y = (xv - mean) * rsqrtf(var + 1e-5f) * g[c] + bvec[c];
    if (residual) y += residual[(size_t)row * C_ + c];
    if (outb) outb[(size_t)row * ldout + c] = f2b(y);
    else      outf[(size_t)row * ldout + c] = y;
}

// ---------------------------------------------------------------------------
// Per (b,h): KV[d][v] = sum_s K[s,d]*V[s,v];  Ksum[d] = sum_s K[s,d]
// (reference /S on V and *S on msg cancel; Z uses unscaled Ksum)
// ---------------------------------------------------------------------------
__global__ __launch_bounds__(256) void kv_kernel(const float* __restrict__ Kb,
                                                 const float* __restrict__ Vb,
                                                 float* __restrict__ KV,
                                                 float* __restrict__ Ksum) {
    int bh = blockIdx.x;
    int b = bh >> 3, h = bh & 7;
    const float* Kp = Kb + (size_t)b * S_ * C_ + h * D_;
    const float* Vp = Vb + (size_t)b * S_ * C_ + h * D_;
    int tid = threadIdx.x;
    __shared__ float Ks[8][32], Vs[8][32];
    int d = tid >> 3, vq = tid & 7;
    int ls = tid >> 5, lc = tid & 31;
    float acc[4] = {0.f, 0.f, 0.f, 0.f};
    float ks = 0.f;
    for (int s0 = 0; s0 < S_; s0 += 8) {
        __syncthreads();
        Ks[ls][lc] = Kp[(size_t)(s0 + ls) * C_ + lc];
        Vs[ls][lc] = Vp[(size_t)(s0 + ls) * C_ + lc];
        __syncthreads();
#pragma unroll
        for (int ss = 0; ss < 8; ++ss) {
            float kd = Ks[ss][d];
            if (vq == 0) ks += kd;
#pragma unroll
            for (int jj = 0; jj < 4; ++jj)
                acc[jj] += kd * Vs[ss][vq * 4 + jj];
        }
    }
    float* kvout = KV + ((size_t)bh * 32 + d) * 32 + vq * 4;
#pragma unroll
    for (int jj = 0; jj < 4; ++jj) kvout[jj] = acc[jj];
    if (vq == 0) Ksum[bh * 32 + d] = ks;
}

// ---------------------------------------------------------------------------
// msg[row, h*32+v] = (sum_d Q*KV) / (sum_d Q*Ksum + eps)  -> bf16
// ---------------------------------------------------------------------------
__global__ __launch_bounds__(256) void msg_kernel(const float* __restrict__ Q,
                                                  const float* __restrict__ KV,
                                                  const float* __restrict__ Ksum,
                                                  ushort* __restrict__ out) {
    int row = blockIdx.x;                // b*N + l
    int b = row >> 12;
    int tid = threadIdx.x;
    __shared__ float Qs[256];
    Qs[tid] = Q[(size_t)row * C_ + tid];
    __syncthreads();
    int h = tid >> 5, v = tid & 31;
    const float* kvp = KV + (size_t)(b * NH_ + h) * 32 * 32;
    const float* ksp = Ksum + (b * NH_ + h) * 32;
    float z = 0.f, m = 0.f;
#pragma unroll
    for (int d = 0; d < 32; ++d) {
        float qd = Qs[h * 32 + d];
        z += qd * ksp[d];
        m += qd * kvp[d * 32 + v];
    }
    out[(size_t)row * C_ + tid] = f2b(m / (z + 1e-6f));
}

// ---------------------------------------------------------------------------
extern "C" void kernel_launch(void* const* d_in, const int* in_sizes, int n_in,
                              void* d_out, int out_size, void* d_ws, size_t ws_size,
                              hipStream_t stream) {
    const float* x      = (const float*)d_in[0];
    const float* sr_w   = (const float*)d_in[1];   // [256,4096] OIHW flat
    const float* sr_b   = (const float*)d_in[2];
    const float* norm_g = (const float*)d_in[3];
    const float* norm_b = (const float*)d_in[4];
    const float* wq     = (const float*)d_in[5];
    const float* wk     = (const float*)d_in[6];
    const float* wv     = (const float*)d_in[7];
    const float* wm     = (const float*)d_in[8];
    const float* w1     = (const float*)d_in[9];   // [512,512]
    const float* w2     = (const float*)d_in[10];  // [256,512]
    const float* n1g    = (const float*)d_in[11];
    const float* n1b    = (const float*)d_in[12];
    const float* n2g    = (const float*)d_in[13];
    const float* n2b    = (const float*)d_in[14];
    float* out = (float*)d_out;

    char* base = (char*)d_ws;
    size_t off = 0;
    auto alloc = [&](size_t bytes) {
        char* p = base + off;
        off += (bytes + 1023) & ~(size_t)1023;
        return p;
    };
    ushort* P16     = (ushort*)alloc(2048ull * 4096 * 2);       // 16.78 MB
    float*  partial = (float*) alloc(8ull * 2048 * 256 * 4);    // 16.78 MB (adjacent to P16)
    ushort* cat     = (ushort*)alloc(32768ull * 512 * 2);       // 33.55 MB
    ushort* src16   = (ushort*)alloc(2048ull * 256 * 2);
    float*  kbuf    = (float*) alloc(2048ull * 256 * 4);
    float*  vbuf    = (float*) alloc(2048ull * 256 * 4);
    float*  qbuf    = (float*) alloc(32768ull * 256 * 4);       // 33.55 MB
    ushort* msg16   = (ushort*)alloc(32768ull * 256 * 2);       // 16.78 MB
    ushort* h1_16   = (ushort*)alloc(32768ull * 512 * 2);       // 33.55 MB
    float*  KV      = (float*) alloc(64ull * 32 * 32 * 4);
    float*  Ksum    = (float*) alloc(64ull * 32 * 4);
    ushort* srw16   = (ushort*)alloc(1048576ull * 2);
    ushort* wq16    = (ushort*)alloc(65536ull * 2);
    ushort* wk16    = (ushort*)alloc(65536ull * 2);
    ushort* wv16    = (ushort*)alloc(65536ull * 2);
    ushort* wm16    = (ushort*)alloc(65536ull * 2);
    ushort* w1_16   = (ushort*)alloc(262144ull * 2);
    ushort* w2_16   = (ushort*)alloc(131072ull * 2);
    // dead-buffer reuse
    float*  merged = qbuf;            // after msg_kernel, qbuf is dead
    float*  h2     = (float*)P16;     // P16+partial (33.55 MB) dead after reduce-LN

    // 0. cast all weights to bf16 in one launch
    CastArgs ca;
    ca.s[0] = sr_w; ca.d[0] = srw16; ca.n4[0] = 1048576 / 4;
    ca.s[1] = wq;   ca.d[1] = wq16;  ca.n4[1] = 65536 / 4;
    ca.s[2] = wk;   ca.d[2] = wk16;  ca.n4[2] = 65536 / 4;
    ca.s[3] = wv;   ca.d[3] = wv16;  ca.n4[3] = 65536 / 4;
    ca.s[4] = wm;   ca.d[4] = wm16;  ca.n4[4] = 65536 / 4;
    ca.s[5] = w1;   ca.d[5] = w1_16; ca.n4[5] = 262144 / 4;
    ca.s[6] = w2;   ca.d[6] = w2_16; ca.n4[6] = 131072 / 4;
    ca.total4 = (1048576 + 4 * 65536 + 262144 + 131072) / 4;
    cast_w_kernel<<<(ca.total4 + 255) / 256, 256, 0, stream>>>(ca);

    // 1. patch gather (bf16) + bf16 x into cat[:, 0:256]
    gather_kernel<<<2048, 256, 0, stream>>>(x, P16, cat);

    // 2. subsample conv GEMM, split-K=8 -> partials; fused reduce+bias+LN -> src16
    { dim3 g(2048 / BM, 256 / BN, 8);
      gemm_bf16<<<g, 256, 0, stream>>>(P16, 4096, srw16, 4096,
                                       partial, nullptr, 256, 512, 0, 2048l * 256); }
    ln_reduce_kernel<<<2048, 256, 0, stream>>>(partial, sr_b, norm_g, norm_b, src16);

    // 3. K/V/Q projections
    { dim3 g(2048 / BM, 256 / BN);
      gemm_bf16<<<g, 256, 0, stream>>>(src16, 256, wk16, 256, kbuf, nullptr, 256, 256, 1, 0); }
    { dim3 g(2048 / BM, 256 / BN);
      gemm_bf16<<<g, 256, 0, stream>>>(src16, 256, wv16, 256, vbuf, nullptr, 256, 256, 0, 0); }
    { dim3 g(32768 / BM, 256 / BN);
      gemm_bf16<<<g, 256, 0, stream>>>(cat, 512, wq16, 256, qbuf, nullptr, 256, 256, 1, 0); }

    // 4. linear attention
    kv_kernel<<<64, 256, 0, stream>>>(kbuf, vbuf, KV, Ksum);
    msg_kernel<<<32768, 256, 0, stream>>>(qbuf, KV, Ksum, msg16);

    // 5. merge proj + LN(norm1) -> bf16 into cat[:, 256:512]
    { dim3 g(32768 / BM, 256 / BN);
      gemm_bf16<<<g, 256, 0, stream>>>(msg16, 256, wm16, 256, merged, nullptr, 256, 256, 0, 0); }
    ln_kernel<<<32768, 256, 0, stream>>>(merged, n1g, n1b, nullptr, nullptr, cat + 256, 512);

    // 6. concat-MLP: single K=512 GEMM (relu, bf16 out), then w2 GEMM
    { dim3 g(32768 / BM, 512 / BN);
      gemm_bf16<<<g, 256, 0, stream>>>(cat, 512, w1_16, 512, nullptr, h1_16, 512, 512, 2, 0); }
    { dim3 g(32768 / BM, 256 / BN);
      gemm_bf16<<<g, 256, 0, stream>>>(h1_16, 512, w2_16, 512, h2, nullptr, 256, 512, 0, 0); }

    // 7. LN(norm2) + residual -> out
    ln_kernel<<<32768, 256, 0, stream>>>(h2, n2g, n2b, x, out, nullptr, 256);
}

// Round 5
// 362.376 us; speedup vs baseline: 3.5552x; 1.1132x over previous
//
#include <hip/hip_runtime.h>
#include <hip/hip_bf16.h>
#include <math.h>

// Problem constants (fixed by the reference)
#define B_   8
#define N_   4096
#define C_   256
#define NH_  8
#define D_   32
#define S_   256      // (64/4)*(64/4)
#define HH_  64       // H = W = 64

#define BM 128
#define BN 128
#define BK 32

typedef __bf16 bf16x8 __attribute__((ext_vector_type(8)));
typedef float f32x4 __attribute__((ext_vector_type(4)));

__device__ inline ushort f2b(float f) {
    __hip_bfloat16 h = __float2bfloat16(f);
    return *reinterpret_cast<ushort*>(&h);
}
__device__ inline float b2f(ushort u) {
    unsigned v = (unsigned)u << 16;
    union { unsigned u; float f; } c; c.u = v; return c.f;
}

__device__ inline void gload16(const void* g, void* l) {
    __builtin_amdgcn_global_load_lds(
        (const __attribute__((address_space(1))) unsigned int*)g,
        (__attribute__((address_space(3))) unsigned int*)l, 16, 0, 0);
}

// ---------------------------------------------------------------------------
// Batched fp32 -> bf16 weight cast (one launch for all 7 weight tensors)
// ---------------------------------------------------------------------------
#define NSEG 7
struct CastArgs {
    const float* s[NSEG];
    ushort*      d[NSEG];
    int          n4[NSEG];   // quads per segment
    int          total4;
};
__global__ __launch_bounds__(256) void cast_w_kernel(CastArgs a) {
    int idx = blockIdx.x * 256 + threadIdx.x;
    if (idx >= a.total4) return;
    int i = idx, s = 0;
    while (i >= a.n4[s]) { i -= a.n4[s]; ++s; }
    float4 f = ((const float4*)a.s[s])[i];
    ushort4 o;
    o.x = f2b(f.x); o.y = f2b(f.y); o.z = f2b(f.z); o.w = f2b(f.w);
    ((ushort4*)a.d[s])[i] = o;
}

// ---------------------------------------------------------------------------
// Gather 4x4xC patches -> P16[b*S+s][c*16+p*4+q] (bf16) AND write bf16 x into
// cat[:, 0:256] (cat is [32768][512] bf16, second half filled by norm1 later).
// ---------------------------------------------------------------------------
__global__ __launch_bounds__(256) void gather_kernel(const float* __restrict__ x,
                                                     ushort* __restrict__ P,
                                                     ushort* __restrict__ cat) {
    int bs = blockIdx.x;                 // b*256 + s
    int b = bs >> 8, s = bs & 255;
    int i = s >> 4, j = s & 15;
    int c = threadIdx.x;
    const float* xb = x + (size_t)b * N_ * C_;
    ushort u[16];
#pragma unroll
    for (int pq = 0; pq < 16; ++pq) {
        int p = pq >> 2, q = pq & 3;
        int n = (i * 4 + p) * HH_ + (j * 4 + q);
        float f = xb[(size_t)n * C_ + c];        // coalesced across c
        u[pq] = f2b(f);
        cat[((size_t)(b * N_ + n)) * 512 + c] = u[pq];   // coalesced across c
    }
    ushort* dst = P + (size_t)bs * 4096 + c * 16;
    ((uint4*)dst)[0] = *(uint4*)&u[0];
    ((uint4*)dst)[1] = *(uint4*)&u[8];
}

// ---------------------------------------------------------------------------
// bf16 MFMA GEMM (NT): C[m,n] = act( sum_k A[m,k] * W[n,k] )
// A [M][lda] bf16 row-major, W [N][ldw] bf16 row-major.
// 128x128 tile, BK=32, 4 waves, 4x4 16x16x32 fragments per wave.
// blockIdx.z = split-K slice (Kchunk each), writes Cf + z*spstride.
// act: 0 none, 1 elu(x)+1, 2 relu.  Output: Cb (bf16) if non-null else Cf.
// ---------------------------------------------------------------------------
__global__ __launch_bounds__(256) void gemm_bf16(
    const ushort* __restrict__ A, int lda,
    const ushort* __restrict__ W, int ldw,
    float* __restrict__ Cf, ushort* __restrict__ Cb, int ldc,
    int Kchunk, int act, long spstride)
{
    __shared__ ushort As[BM * BK];   // 8 KB, row-major [128][32]
    __shared__ ushort Bs[BN * BK];   // 8 KB
    const int t = threadIdx.x;
    const int lane = t & 63;
    const int w = t >> 6;
    const int wr = w >> 1, wc = w & 1;           // wave -> 64x64 quadrant
    const int fr = lane & 15, fq = lane >> 4;    // fragment row / k-group
    const int bm = blockIdx.x * BM, bn = blockIdx.y * BN;
    const long koff = (long)blockIdx.z * Kchunk;

    f32x4 acc[4][4] = {};

    const ushort* Ag = A + (size_t)bm * lda + koff;
    const ushort* Wg = W + (size_t)bn * ldw + koff;
    char* AsB = (char*)As;
    char* BsB = (char*)Bs;
    const int wuni = (t & ~63) * 16;             // wave-uniform LDS byte base

    for (int k0 = 0; k0 < Kchunk; k0 += BK) {
        // stage A,B tiles (8 KB each): 2 x 256 chunks of 16 B per tile
#pragma unroll
        for (int i = 0; i < 2; ++i) {
            int c = i * 256 + t;
            int row = c >> 2, kb = (c & 3) * 8;
            gload16(Ag + (size_t)row * lda + k0 + kb, AsB + i * 4096 + wuni);
            gload16(Wg + (size_t)row * ldw + k0 + kb, BsB + i * 4096 + wuni);
        }
        __syncthreads();   // compiler drains vmcnt(0) before barrier

        bf16x8 af[4], bv[4];
#pragma unroll
        for (int m = 0; m < 4; ++m)
            af[m] = *(const bf16x8*)&As[(wr * 64 + m * 16 + fr) * BK + fq * 8];
#pragma unroll
        for (int n = 0; n < 4; ++n)
            bv[n] = *(const bf16x8*)&Bs[(wc * 64 + n * 16 + fr) * BK + fq * 8];
#pragma unroll
        for (int m = 0; m < 4; ++m)
#pragma unroll
            for (int n = 0; n < 4; ++n)
                acc[m][n] = __builtin_amdgcn_mfma_f32_16x16x32_bf16(
                    af[m], bv[n], acc[m][n], 0, 0, 0);
        __syncthreads();
    }

    float* Cfz = Cf ? Cf + (size_t)blockIdx.z * spstride : nullptr;
#pragma unroll
    for (int m = 0; m < 4; ++m) {
#pragma unroll
        for (int n = 0; n < 4; ++n) {
            int col = bn + wc * 64 + n * 16 + fr;
#pragma unroll
            for (int i = 0; i < 4; ++i) {
                int row = bm + wr * 64 + m * 16 + fq * 4 + i;
                float v = acc[m][n][i];
                if (act == 1) v = v > 0.f ? v + 1.f : __expf(v);   // elu(x)+1
                else if (act == 2) v = fmaxf(v, 0.f);
                if (Cb) Cb[(size_t)row * ldc + col] = f2b(v);
                else    Cfz[(size_t)row * ldc + col] = v;
            }
        }
    }
}

// ---------------------------------------------------------------------------
// Sum 8 split-K partials + conv bias, then LayerNorm -> bf16 src
// ---------------------------------------------------------------------------
__global__ __launch_bounds__(256) void ln_reduce_kernel(
    const float* __restrict__ part,     // [8][2048][256]
    const float* __restrict__ bias,
    const float* __restrict__ g, const float* __restrict__ bvec,
    ushort* __restrict__ outb)
{
    int row = blockIdx.x, c = threadIdx.x;
    float v = bias[c];
#pragma unroll
    for (int s = 0; s < 8; ++s)
        v += part[(size_t)s * 2048 * 256 + (size_t)row * 256 + c];
    __shared__ float r1[256], r2[256];
    r1[c] = v; r2[c] = v * v;
    __syncthreads();
    for (int off = 128; off > 0; off >>= 1) {
        if (c < off) { r1[c] += r1[c + off]; r2[c] += r2[c + off]; }
        __syncthreads();
    }
    float mean = r1[0] * (1.f / C_);
    float var  = r2[0] * (1.f / C_) - mean * mean;
    float y = (v - mean) * rsqrtf(var + 1e-5f) * g[c] + bvec[c];
    outb[(size_t)row * C_ + c] = f2b(y);
}

// ---------------------------------------------------------------------------
// LayerNorm over C=256. Input: bf16 (inb) if non-null else fp32 (inf).
// Optional fp32 residual. Output: bf16 (outb, ld=ldout) if non-null else fp32.
// ---------------------------------------------------------------------------
__global__ __launch_bounds__(256) void ln_kernel(
    const float* __restrict__ inf, const ushort* __restrict__ inb,
    const float* __restrict__ g, const float* __restrict__ bvec,
    const float* __restrict__ residual,
    float* __restrict__ outf, ushort* __restrict__ outb, int ldout)
{
    int row = blockIdx.x, c = threadIdx.x;
    float xv = inb ? b2f(inb[(size_t)row * C_ + c]) : inf[(size_t)row * C_ + c];
    __shared__ float r1[256], r2[256];
    r1[c] = xv; r2[c] = xv * xv;
    __syncthreads();
    for (int off = 128; off > 0; off >>= 1) {
        if (c < off) { r1[c] += r1[c + off]; r2[c] += r2[c + off]; }
        __syncthreads();
    }
    float mean = r1[0] * (1.f / C_);
    float var  = r2[0] * (1.f / C_) - mean * mean;
    float y = (xv - mean) * rsqrtf(var + 1e-5f) * g[c] + bvec[c];
    if (residual) y += residual[(size_t)row * C_ + c];
    if (outb) outb[(size_t)row * ldout + c] = f2b(y);
    else      outf[(size_t)row * ldout + c] = y;
}

// ---------------------------------------------------------------------------
// Per (b,h): KV[d][v] = sum_s K[s,d]*V[s,v];  Ksum[d] = sum_s K[s,d]
// (reference /S on V and *S on msg cancel; Z uses unscaled Ksum)
// ---------------------------------------------------------------------------
__global__ __launch_bounds__(256) void kv_kernel(const float* __restrict__ Kb,
                                                 const float* __restrict__ Vb,
                                                 float* __restrict__ KV,
                                                 float* __restrict__ Ksum) {
    int bh = blockIdx.x;
    int b = bh >> 3, h = bh & 7;
    const float* Kp = Kb + (size_t)b * S_ * C_ + h * D_;
    const float* Vp = Vb + (size_t)b * S_ * C_ + h * D_;
    int tid = threadIdx.x;
    __shared__ float Ks[8][32], Vs[8][32];
    int d = tid >> 3, vq = tid & 7;
    int ls = tid >> 5, lc = tid & 31;
    float acc[4] = {0.f, 0.f, 0.f, 0.f};
    float ks = 0.f;
    for (int s0 = 0; s0 < S_; s0 += 8) {
        __syncthreads();
        Ks[ls][lc] = Kp[(size_t)(s0 + ls) * C_ + lc];
        Vs[ls][lc] = Vp[(size_t)(s0 + ls) * C_ + lc];
        __syncthreads();
#pragma unroll
        for (int ss = 0; ss < 8; ++ss) {
            float kd = Ks[ss][d];
            if (vq == 0) ks += kd;
#pragma unroll
            for (int jj = 0; jj < 4; ++jj)
                acc[jj] += kd * Vs[ss][vq * 4 + jj];
        }
    }
    float* kvout = KV + ((size_t)bh * 32 + d) * 32 + vq * 4;
#pragma unroll
    for (int jj = 0; jj < 4; ++jj) kvout[jj] = acc[jj];
    if (vq == 0) Ksum[bh * 32 + d] = ks;
}

// ---------------------------------------------------------------------------
// msg[row, h*32+v] = (Q·KV[h,:,v]) / (Q·Ksum[h] + eps), Q bf16.
// Block = 64 rows of one b. KV+Ksum staged LDS once -> per-thread registers
// (fixed h,v per thread). Q rows streamed through LDS 8 at a time.
// ---------------------------------------------------------------------------
__global__ __launch_bounds__(256) void msg_kernel(const ushort* __restrict__ Q,
                                                  const float* __restrict__ KV,
                                                  const float* __restrict__ Ksum,
                                                  ushort* __restrict__ out) {
    const int row0 = blockIdx.x * 64;        // 4096 % 64 == 0: never crosses b
    const int b = row0 >> 12;
    const int tid = threadIdx.x;
    const int h = tid >> 5, v = tid & 31;
    __shared__ float KVs[8192];              // [h][d][v]  32 KB
    __shared__ float Kss[256];               // [h][d]      1 KB
    __shared__ ushort Qs[8][256];            //             4 KB
    const float4* kvsrc = (const float4*)(KV + (size_t)b * 8192);
#pragma unroll
    for (int i = 0; i < 8; ++i)
        ((float4*)KVs)[i * 256 + tid] = kvsrc[i * 256 + tid];
    if (tid < 64)
        ((float4*)Kss)[tid] = ((const float4*)(Ksum + b * 256))[tid];
    __syncthreads();
    float kvr[32], ksr[32];                  // this thread's KV column / Ksum row
#pragma unroll
    for (int d = 0; d < 32; ++d) {
        kvr[d] = KVs[h * 1024 + d * 32 + v];
        ksr[d] = Kss[h * 32 + d];
    }
    for (int r0 = 0; r0 < 64; r0 += 8) {
        __syncthreads();
        { int r = tid >> 5, c8 = (tid & 31) * 8;
          *(uint4*)&Qs[r][c8] = *(const uint4*)&Q[(size_t)(row0 + r0 + r) * 256 + c8]; }
        __syncthreads();
#pragma unroll
        for (int r = 0; r < 8; ++r) {
            ushort q[32];
            *(uint4*)&q[0]  = *(const uint4*)&Qs[r][h * 32 + 0];
            *(uint4*)&q[8]  = *(const uint4*)&Qs[r][h * 32 + 8];
            *(uint4*)&q[16] = *(const uint4*)&Qs[r][h * 32 + 16];
            *(uint4*)&q[24] = *(const uint4*)&Qs[r][h * 32 + 24];
            float z = 1e-6f, m = 0.f;
#pragma unroll
            for (int d = 0; d < 32; ++d) {
                float qd = b2f(q[d]);
                z = fmaf(qd, ksr[d], z);
                m = fmaf(qd, kvr[d], m);
            }
            out[(size_t)(row0 + r0 + r) * 256 + tid] = f2b(m / z);
        }
    }
}

// ---------------------------------------------------------------------------
extern "C" void kernel_launch(void* const* d_in, const int* in_sizes, int n_in,
                              void* d_out, int out_size, void* d_ws, size_t ws_size,
                              hipStream_t stream) {
    const float* x      = (const float*)d_in[0];
    const float* sr_w   = (const float*)d_in[1];   // [256,4096] OIHW flat
    const float* sr_b   = (const float*)d_in[2];
    const float* norm_g = (const float*)d_in[3];
    const float* norm_b = (const float*)d_in[4];
    const float* wq     = (const float*)d_in[5];
    const float* wk     = (const float*)d_in[6];
    const float* wv     = (const float*)d_in[7];
    const float* wm     = (const float*)d_in[8];
    const float* w1     = (const float*)d_in[9];   // [512,512]
    const float* w2     = (const float*)d_in[10];  // [256,512]
    const float* n1g    = (const float*)d_in[11];
    const float* n1b    = (const float*)d_in[12];
    const float* n2g    = (const float*)d_in[13];
    const float* n2b    = (const float*)d_in[14];
    float* out = (float*)d_out;

    char* base = (char*)d_ws;
    size_t off = 0;
    auto alloc = [&](size_t bytes) {
        char* p = base + off;
        off += (bytes + 1023) & ~(size_t)1023;
        return p;
    };
    ushort* P16      = (ushort*)alloc(2048ull * 4096 * 2);       // 16.8 MB
    float*  partial  = (float*) alloc(8ull * 2048 * 256 * 4);    // 16.8 MB
    ushort* cat      = (ushort*)alloc(32768ull * 512 * 2);       // 33.6 MB
    ushort* src16    = (ushort*)alloc(2048ull * 256 * 2);
    float*  kbuf     = (float*) alloc(2048ull * 256 * 4);
    float*  vbuf     = (float*) alloc(2048ull * 256 * 4);
    ushort* qbuf16   = (ushort*)alloc(32768ull * 256 * 2);       // 16.8 MB
    ushort* msg16    = (ushort*)alloc(32768ull * 256 * 2);       // 16.8 MB
    ushort* merged16 = (ushort*)alloc(32768ull * 256 * 2);       // 16.8 MB
    ushort* h1_16    = (ushort*)alloc(32768ull * 512 * 2);       // 33.6 MB
    float*  KV       = (float*) alloc(64ull * 32 * 32 * 4);
    float*  Ksum     = (float*) alloc(64ull * 32 * 4);
    ushort* srw16    = (ushort*)alloc(1048576ull * 2);
    ushort* wq16     = (ushort*)alloc(65536ull * 2);
    ushort* wk16     = (ushort*)alloc(65536ull * 2);
    ushort* wv16     = (ushort*)alloc(65536ull * 2);
    ushort* wm16     = (ushort*)alloc(65536ull * 2);
    ushort* w1_16    = (ushort*)alloc(262144ull * 2);
    ushort* w2_16    = (ushort*)alloc(131072ull * 2);
    // dead-buffer reuse: P16 (+partial) dead after ln_reduce -> h2 bf16 lives there
    ushort* h2_16 = P16;

    // 0. cast all weights to bf16 in one launch
    CastArgs ca;
    ca.s[0] = sr_w; ca.d[0] = srw16; ca.n4[0] = 1048576 / 4;
    ca.s[1] = wq;   ca.d[1] = wq16;  ca.n4[1] = 65536 / 4;
    ca.s[2] = wk;   ca.d[2] = wk16;  ca.n4[2] = 65536 / 4;
    ca.s[3] = wv;   ca.d[3] = wv16;  ca.n4[3] = 65536 / 4;
    ca.s[4] = wm;   ca.d[4] = wm16;  ca.n4[4] = 65536 / 4;
    ca.s[5] = w1;   ca.d[5] = w1_16; ca.n4[5] = 262144 / 4;
    ca.s[6] = w2;   ca.d[6] = w2_16; ca.n4[6] = 131072 / 4;
    ca.total4 = (1048576 + 4 * 65536 + 262144 + 131072) / 4;
    cast_w_kernel<<<(ca.total4 + 255) / 256, 256, 0, stream>>>(ca);

    // 1. patch gather (bf16) + bf16 x into cat[:, 0:256]
    gather_kernel<<<2048, 256, 0, stream>>>(x, P16, cat);

    // 2. subsample conv GEMM, split-K=8 -> partials; fused reduce+bias+LN -> src16
    { dim3 g(2048 / BM, 256 / BN, 8);
      gemm_bf16<<<g, 256, 0, stream>>>(P16, 4096, srw16, 4096,
                                       partial, nullptr, 256, 512, 0, 2048l * 256); }
    ln_reduce_kernel<<<2048, 256, 0, stream>>>(partial, sr_b, norm_g, norm_b, src16);

    // 3. K/V/Q projections (Q reads cat[:,0:256] with lda=512, K=256; bf16 out)
    { dim3 g(2048 / BM, 256 / BN);
      gemm_bf16<<<g, 256, 0, stream>>>(src16, 256, wk16, 256, kbuf, nullptr, 256, 256, 1, 0); }
    { dim3 g(2048 / BM, 256 / BN);
      gemm_bf16<<<g, 256, 0, stream>>>(src16, 256, wv16, 256, vbuf, nullptr, 256, 256, 0, 0); }
    { dim3 g(32768 / BM, 256 / BN);
      gemm_bf16<<<g, 256, 0, stream>>>(cat, 512, wq16, 256, nullptr, qbuf16, 256, 256, 1, 0); }

    // 4. linear attention
    kv_kernel<<<64, 256, 0, stream>>>(kbuf, vbuf, KV, Ksum);
    msg_kernel<<<512, 256, 0, stream>>>(qbuf16, KV, Ksum, msg16);

    // 5. merge proj (bf16 out) + LN(norm1) -> bf16 into cat[:, 256:512]
    { dim3 g(32768 / BM, 256 / BN);
      gemm_bf16<<<g, 256, 0, stream>>>(msg16, 256, wm16, 256, nullptr, merged16, 256, 256, 0, 0); }
    ln_kernel<<<32768, 256, 0, stream>>>(nullptr, merged16, n1g, n1b, nullptr,
                                         nullptr, cat + 256, 512);

    // 6. concat-MLP: single K=512 GEMM (relu, bf16 out), then w2 GEMM (bf16 out)
    { dim3 g(32768 / BM, 512 / BN);
      gemm_bf16<<<g, 256, 0, stream>>>(cat, 512, w1_16, 512, nullptr, h1_16, 512, 512, 2, 0); }
    { dim3 g(32768 / BM, 256 / BN);
      gemm_bf16<<<g, 256, 0, stream>>>(h1_16, 512, w2_16, 512, nullptr, h2_16, 256, 512, 0, 0); }

    // 7. LN(norm2) + residual -> out (fp32)
    ln_kernel<<<32768, 256, 0, stream>>>(nullptr, h2_16, n2g, n2b, x, out, nullptr, 256);
}

// Round 6
// 311.139 us; speedup vs baseline: 4.1406x; 1.1647x over previous
//
#include <hip/hip_runtime.h>
#include <hip/hip_bf16.h>
#include <math.h>

// Problem constants (fixed by the reference)
#define B_   8
#define N_   4096
#define C_   256
#define NH_  8
#define D_   32
#define S_   256      // (64/4)*(64/4)
#define HH_  64       // H = W = 64

#define BM 128
#define BN 128
#define BK 32

typedef __bf16 bf16x8 __attribute__((ext_vector_type(8)));
typedef float f32x4 __attribute__((ext_vector_type(4)));

__device__ inline ushort f2b(float f) {
    __hip_bfloat16 h = __float2bfloat16(f);
    return *reinterpret_cast<ushort*>(&h);
}
__device__ inline float b2f(ushort u) {
    unsigned v = (unsigned)u << 16;
    union { unsigned u; float f; } c; c.u = v; return c.f;
}

__device__ inline void gload16(const void* g, void* l) {
    __builtin_amdgcn_global_load_lds(
        (const __attribute__((address_space(1))) unsigned int*)g,
        (__attribute__((address_space(3))) unsigned int*)l, 16, 0, 0);
}

// ---------------------------------------------------------------------------
// Batched fp32 -> bf16 weight cast (one launch for all weight tensors)
// ---------------------------------------------------------------------------
#define NSEG 7
struct CastArgs {
    const float* s[NSEG];
    ushort*      d[NSEG];
    int          n4[NSEG];   // quads per segment
    int          total4;
};
__global__ __launch_bounds__(256) void cast_w_kernel(CastArgs a) {
    int idx = blockIdx.x * 256 + threadIdx.x;
    if (idx >= a.total4) return;
    int i = idx, s = 0;
    while (i >= a.n4[s]) { i -= a.n4[s]; ++s; }
    float4 f = ((const float4*)a.s[s])[i];
    ushort4 o;
    o.x = f2b(f.x); o.y = f2b(f.y); o.z = f2b(f.z); o.w = f2b(f.w);
    ((ushort4*)a.d[s])[i] = o;
}

// ---------------------------------------------------------------------------
// Gather 4x4xC patches -> P16[b*S+s][c*16+p*4+q] (bf16) AND write bf16 x into
// cat[:, 0:256] (cat is [32768][512] bf16, second half filled by norm1 later).
// ---------------------------------------------------------------------------
__global__ __launch_bounds__(256) void gather_kernel(const float* __restrict__ x,
                                                     ushort* __restrict__ P,
                                                     ushort* __restrict__ cat) {
    int bs = blockIdx.x;                 // b*256 + s
    int b = bs >> 8, s = bs & 255;
    int i = s >> 4, j = s & 15;
    int c = threadIdx.x;
    const float* xb = x + (size_t)b * N_ * C_;
    ushort u[16];
#pragma unroll
    for (int pq = 0; pq < 16; ++pq) {
        int p = pq >> 2, q = pq & 3;
        int n = (i * 4 + p) * HH_ + (j * 4 + q);
        float f = xb[(size_t)n * C_ + c];        // coalesced across c
        u[pq] = f2b(f);
        cat[((size_t)(b * N_ + n)) * 512 + c] = u[pq];   // coalesced across c
    }
    ushort* dst = P + (size_t)bs * 4096 + c * 16;
    ((uint4*)dst)[0] = *(uint4*)&u[0];
    ((uint4*)dst)[1] = *(uint4*)&u[8];
}

// ---------------------------------------------------------------------------
// bf16 MFMA GEMM (NT): C[m,n] = act( sum_k A[m,k] * W[n,k] )
// 128x128 tile, BK=32, 4 waves, 4x4 16x16x32 fragments per wave.
// LDS tiles XOR-swizzled (T2, rule 21): dest linear, source column pre-swizzled
// with kb ^= (row&3)*8; reads apply the same XOR. Kills the 8-way bank
// conflict of 64B-row [128][32] tiles.
// blockIdx.z = split-K slice (Kchunk each), writes Cf + z*spstride.
// act: 0 none, 1 elu(x)+1, 2 relu, 3 elu+1 if col<256 else none.
// Output: Cb (bf16) if non-null else Cf (fp32).
// ---------------------------------------------------------------------------
__global__ __launch_bounds__(256) void gemm_bf16(
    const ushort* __restrict__ A, int lda,
    const ushort* __restrict__ W, int ldw,
    float* __restrict__ Cf, ushort* __restrict__ Cb, int ldc,
    int Kchunk, int act, long spstride)
{
    __shared__ ushort As[BM * BK];   // 8 KB, row-major [128][32] (swizzled)
    __shared__ ushort Bs[BN * BK];   // 8 KB
    const int t = threadIdx.x;
    const int lane = t & 63;
    const int w = t >> 6;
    const int wr = w >> 1, wc = w & 1;           // wave -> 64x64 quadrant
    const int fr = lane & 15, fq = lane >> 4;    // fragment row / k-group
    const int bm = blockIdx.x * BM, bn = blockIdx.y * BN;
    const long koff = (long)blockIdx.z * Kchunk;

    f32x4 acc[4][4] = {};

    const ushort* Ag = A + (size_t)bm * lda + koff;
    const ushort* Wg = W + (size_t)bn * ldw + koff;
    char* AsB = (char*)As;
    char* BsB = (char*)Bs;
    const int wuni = (t & ~63) * 16;             // wave-uniform LDS byte base

    // staging decomposition: chunk c = i*256+t -> row=c>>2, 16B col kb=(c&3)*8
    const int srow = t >> 2;
    const int skb0 = ((t & 3) * 8) ^ ((srow & 3) * 8);   // pre-swizzled source col

    for (int k0 = 0; k0 < Kchunk; k0 += BK) {
#pragma unroll
        for (int i = 0; i < 2; ++i) {
            int row = i * 64 + srow;
            gload16(Ag + (size_t)row * lda + k0 + skb0, AsB + i * 4096 + wuni);
            gload16(Wg + (size_t)row * ldw + k0 + skb0, BsB + i * 4096 + wuni);
        }
        __syncthreads();   // compiler drains vmcnt(0) before barrier

        bf16x8 af[4], bv[4];
#pragma unroll
        for (int m = 0; m < 4; ++m) {
            int ra = wr * 64 + m * 16 + fr;
            af[m] = *(const bf16x8*)&As[ra * BK + (fq * 8 ^ ((ra & 3) * 8))];
        }
#pragma unroll
        for (int n = 0; n < 4; ++n) {
            int rb = wc * 64 + n * 16 + fr;
            bv[n] = *(const bf16x8*)&Bs[rb * BK + (fq * 8 ^ ((rb & 3) * 8))];
        }
#pragma unroll
        for (int m = 0; m < 4; ++m)
#pragma unroll
            for (int n = 0; n < 4; ++n)
                acc[m][n] = __builtin_amdgcn_mfma_f32_16x16x32_bf16(
                    af[m], bv[n], acc[m][n], 0, 0, 0);
        __syncthreads();
    }

    float* Cfz = Cf ? Cf + (size_t)blockIdx.z * spstride : nullptr;
#pragma unroll
    for (int m = 0; m < 4; ++m) {
#pragma unroll
        for (int n = 0; n < 4; ++n) {
            int col = bn + wc * 64 + n * 16 + fr;
#pragma unroll
            for (int i = 0; i < 4; ++i) {
                int row = bm + wr * 64 + m * 16 + fq * 4 + i;
                float v = acc[m][n][i];
                if (act == 1 || (act == 3 && col < 256))
                    v = v > 0.f ? v + 1.f : __expf(v);   // elu(x)+1
                else if (act == 2) v = fmaxf(v, 0.f);
                if (Cb) Cb[(size_t)row * ldc + col] = f2b(v);
                else    Cfz[(size_t)row * ldc + col] = v;
            }
        }
    }
}

// ---------------------------------------------------------------------------
// Sum 8 split-K partials + conv bias, then LayerNorm -> bf16 src.
// Wave-per-row: 4 rows/block, lane owns 4 cols, shfl_xor reduction.
// ---------------------------------------------------------------------------
__global__ __launch_bounds__(256) void ln_reduce_kernel(
    const float* __restrict__ part,     // [8][2048][256]
    const float* __restrict__ bias,
    const float* __restrict__ g, const float* __restrict__ bvec,
    ushort* __restrict__ outb)
{
    int row = blockIdx.x * 4 + (threadIdx.x >> 6);
    int lane = threadIdx.x & 63;
    int c0 = lane * 4;
    float4 v = *(const float4*)&bias[c0];
#pragma unroll
    for (int s = 0; s < 8; ++s) {
        float4 p = *(const float4*)&part[(size_t)s * 2048 * 256 + (size_t)row * 256 + c0];
        v.x += p.x; v.y += p.y; v.z += p.z; v.w += p.w;
    }
    float s1 = v.x + v.y + v.z + v.w;
    float s2 = v.x * v.x + v.y * v.y + v.z * v.z + v.w * v.w;
#pragma unroll
    for (int m = 1; m < 64; m <<= 1) {
        s1 += __shfl_xor(s1, m);
        s2 += __shfl_xor(s2, m);
    }
    float mean = s1 * (1.f / C_);
    float rstd = rsqrtf(s2 * (1.f / C_) - mean * mean + 1e-5f);
    float4 gv = *(const float4*)&g[c0];
    float4 bb = *(const float4*)&bvec[c0];
    ushort4 o;
    o.x = f2b((v.x - mean) * rstd * gv.x + bb.x);
    o.y = f2b((v.y - mean) * rstd * gv.y + bb.y);
    o.z = f2b((v.z - mean) * rstd * gv.z + bb.z);
    o.w = f2b((v.w - mean) * rstd * gv.w + bb.w);
    *(ushort4*)&outb[(size_t)row * C_ + c0] = o;
}

// ---------------------------------------------------------------------------
// LayerNorm over C=256, bf16 input. Wave-per-row (4 rows/block, no LDS).
// Optional fp32 residual. Output bf16 (outb, ld=ldout) or fp32 (outf).
// ---------------------------------------------------------------------------
__global__ __launch_bounds__(256) void ln_kernel(
    const ushort* __restrict__ inb,
    const float* __restrict__ g, const float* __restrict__ bvec,
    const float* __restrict__ residual,
    float* __restrict__ outf, ushort* __restrict__ outb, int ldout)
{
    int row = blockIdx.x * 4 + (threadIdx.x >> 6);
    int lane = threadIdx.x & 63;
    int c0 = lane * 4;
    ushort4 u = *(const ushort4*)&inb[(size_t)row * C_ + c0];
    float x0 = b2f(u.x), x1 = b2f(u.y), x2 = b2f(u.z), x3 = b2f(u.w);
    float s1 = x0 + x1 + x2 + x3;
    float s2 = x0 * x0 + x1 * x1 + x2 * x2 + x3 * x3;
#pragma unroll
    for (int m = 1; m < 64; m <<= 1) {
        s1 += __shfl_xor(s1, m);
        s2 += __shfl_xor(s2, m);
    }
    float mean = s1 * (1.f / C_);
    float rstd = rsqrtf(s2 * (1.f / C_) - mean * mean + 1e-5f);
    float4 gv = *(const float4*)&g[c0];
    float4 bb = *(const float4*)&bvec[c0];
    float y0 = (x0 - mean) * rstd * gv.x + bb.x;
    float y1 = (x1 - mean) * rstd * gv.y + bb.y;
    float y2 = (x2 - mean) * rstd * gv.z + bb.z;
    float y3 = (x3 - mean) * rstd * gv.w + bb.w;
    if (residual) {
        float4 r = *(const float4*)&residual[(size_t)row * C_ + c0];
        y0 += r.x; y1 += r.y; y2 += r.z; y3 += r.w;
    }
    if (outb) {
        ushort4 o; o.x = f2b(y0); o.y = f2b(y1); o.z = f2b(y2); o.w = f2b(y3);
        *(ushort4*)&outb[(size_t)row * ldout + c0] = o;
    } else {
        *(float4*)&outf[(size_t)row * ldout + c0] = make_float4(y0, y1, y2, y3);
    }
}

// ---------------------------------------------------------------------------
// Per (b,h): KV[d][v] = sum_s K[s,d]*V[s,v];  Ksum[d] = sum_s K[s,d]
// Input: fused kv16 [2048][512] bf16 (cols 0:256 = K heads, 256:512 = V heads)
// (reference /S on V and *S on msg cancel; Z uses unscaled Ksum)
// ---------------------------------------------------------------------------
__global__ __launch_bounds__(256) void kv_kernel(const ushort* __restrict__ kvin,
                                                 float* __restrict__ KV,
                                                 float* __restrict__ Ksum) {
    int bh = blockIdx.x;
    int b = bh >> 3, h = bh & 7;
    const ushort* Kp = kvin + (size_t)b * S_ * 512 + h * D_;
    const ushort* Vp = Kp + 256;
    int tid = threadIdx.x;
    __shared__ float Ks[8][32], Vs[8][32];
    int d = tid >> 3, vq = tid & 7;
    int ls = tid >> 5, lc = tid & 31;
    float acc[4] = {0.f, 0.f, 0.f, 0.f};
    float ks = 0.f;
    for (int s0 = 0; s0 < S_; s0 += 8) {
        __syncthreads();
        Ks[ls][lc] = b2f(Kp[(size_t)(s0 + ls) * 512 + lc]);
        Vs[ls][lc] = b2f(Vp[(size_t)(s0 + ls) * 512 + lc]);
        __syncthreads();
#pragma unroll
        for (int ss = 0; ss < 8; ++ss) {
            float kd = Ks[ss][d];
            if (vq == 0) ks += kd;
#pragma unroll
            for (int jj = 0; jj < 4; ++jj)
                acc[jj] += kd * Vs[ss][vq * 4 + jj];
        }
    }
    float* kvout = KV + ((size_t)bh * 32 + d) * 32 + vq * 4;
#pragma unroll
    for (int jj = 0; jj < 4; ++jj) kvout[jj] = acc[jj];
    if (vq == 0) Ksum[bh * 32 + d] = ks;
}

// ---------------------------------------------------------------------------
// msg[row, h*32+v] = (Q·KV[h,:,v]) / (Q·Ksum[h] + eps), Q bf16.
// Block = 64 rows of one b. KV+Ksum staged LDS once -> per-thread registers
// (fixed h,v per thread). Q rows streamed through LDS 8 at a time.
// ---------------------------------------------------------------------------
__global__ __launch_bounds__(256) void msg_kernel(const ushort* __restrict__ Q,
                                                  const float* __restrict__ KV,
                                                  const float* __restrict__ Ksum,
                                                  ushort* __restrict__ out) {
    const int row0 = blockIdx.x * 64;        // 4096 % 64 == 0: never crosses b
    const int b = row0 >> 12;
    const int tid = threadIdx.x;
    const int h = tid >> 5, v = tid & 31;
    __shared__ float KVs[8192];              // [h][d][v]  32 KB
    __shared__ float Kss[256];               // [h][d]      1 KB
    __shared__ ushort Qs[8][256];            //             4 KB
    const float4* kvsrc = (const float4*)(KV + (size_t)b * 8192);
#pragma unroll
    for (int i = 0; i < 8; ++i)
        ((float4*)KVs)[i * 256 + tid] = kvsrc[i * 256 + tid];
    if (tid < 64)
        ((float4*)Kss)[tid] = ((const float4*)(Ksum + b * 256))[tid];
    __syncthreads();
    float kvr[32], ksr[32];                  // this thread's KV column / Ksum row
#pragma unroll
    for (int d = 0; d < 32; ++d) {
        kvr[d] = KVs[h * 1024 + d * 32 + v];
        ksr[d] = Kss[h * 32 + d];
    }
    for (int r0 = 0; r0 < 64; r0 += 8) {
        __syncthreads();
        { int r = tid >> 5, c8 = (tid & 31) * 8;
          *(uint4*)&Qs[r][c8] = *(const uint4*)&Q[(size_t)(row0 + r0 + r) * 256 + c8]; }
        __syncthreads();
#pragma unroll
        for (int r = 0; r < 8; ++r) {
            ushort q[32];
            *(uint4*)&q[0]  = *(const uint4*)&Qs[r][h * 32 + 0];
            *(uint4*)&q[8]  = *(const uint4*)&Qs[r][h * 32 + 8];
            *(uint4*)&q[16] = *(const uint4*)&Qs[r][h * 32 + 16];
            *(uint4*)&q[24] = *(const uint4*)&Qs[r][h * 32 + 24];
            float z = 1e-6f, m = 0.f;
#pragma unroll
            for (int d = 0; d < 32; ++d) {
                float qd = b2f(q[d]);
                z = fmaf(qd, ksr[d], z);
                m = fmaf(qd, kvr[d], m);
            }
            out[(size_t)(row0 + r0 + r) * 256 + tid] = f2b(m / z);
        }
    }
}

// ---------------------------------------------------------------------------
extern "C" void kernel_launch(void* const* d_in, const int* in_sizes, int n_in,
                              void* d_out, int out_size, void* d_ws, size_t ws_size,
                              hipStream_t stream) {
    const float* x      = (const float*)d_in[0];
    const float* sr_w   = (const float*)d_in[1];   // [256,4096] OIHW flat
    const float* sr_b   = (const float*)d_in[2];
    const float* norm_g = (const float*)d_in[3];
    const float* norm_b = (const float*)d_in[4];
    const float* wq     = (const float*)d_in[5];
    const float* wk     = (const float*)d_in[6];
    const float* wv     = (const float*)d_in[7];
    const float* wm     = (const float*)d_in[8];
    const float* w1     = (const float*)d_in[9];   // [512,512]
    const float* w2     = (const float*)d_in[10];  // [256,512]
    const float* n1g    = (const float*)d_in[11];
    const float* n1b    = (const float*)d_in[12];
    const float* n2g    = (const float*)d_in[13];
    const float* n2b    = (const float*)d_in[14];
    float* out = (float*)d_out;

    char* base = (char*)d_ws;
    size_t off = 0;
    auto alloc = [&](size_t bytes) {
        char* p = base + off;
        off += (bytes + 1023) & ~(size_t)1023;
        return p;
    };
    ushort* P16      = (ushort*)alloc(2048ull * 4096 * 2);       // 16.8 MB
    float*  partial  = (float*) alloc(8ull * 2048 * 256 * 4);    // 16.8 MB
    ushort* cat      = (ushort*)alloc(32768ull * 512 * 2);       // 33.6 MB
    ushort* src16    = (ushort*)alloc(2048ull * 256 * 2);
    ushort* kv16     = (ushort*)alloc(2048ull * 512 * 2);        // 2.1 MB
    ushort* qbuf16   = (ushort*)alloc(32768ull * 256 * 2);       // 16.8 MB
    ushort* msg16    = (ushort*)alloc(32768ull * 256 * 2);       // 16.8 MB
    ushort* merged16 = (ushort*)alloc(32768ull * 256 * 2);       // 16.8 MB
    ushort* h1_16    = (ushort*)alloc(32768ull * 512 * 2);       // 33.6 MB
    float*  KV       = (float*) alloc(64ull * 32 * 32 * 4);
    float*  Ksum     = (float*) alloc(64ull * 32 * 4);
    ushort* srw16    = (ushort*)alloc(1048576ull * 2);
    ushort* wq16     = (ushort*)alloc(65536ull * 2);
    ushort* wkv16    = (ushort*)alloc(131072ull * 2);            // [wk;wv] stacked
    ushort* wm16     = (ushort*)alloc(65536ull * 2);
    ushort* w1_16    = (ushort*)alloc(262144ull * 2);
    ushort* w2_16    = (ushort*)alloc(131072ull * 2);
    // dead-buffer reuse: P16 (+partial) dead after ln_reduce -> h2 bf16 lives there
    ushort* h2_16 = P16;

    // 0. cast all weights to bf16 in one launch (wk,wv -> stacked wkv16)
    CastArgs ca;
    ca.s[0] = sr_w; ca.d[0] = srw16;         ca.n4[0] = 1048576 / 4;
    ca.s[1] = wq;   ca.d[1] = wq16;          ca.n4[1] = 65536 / 4;
    ca.s[2] = wk;   ca.d[2] = wkv16;         ca.n4[2] = 65536 / 4;
    ca.s[3] = wv;   ca.d[3] = wkv16 + 65536; ca.n4[3] = 65536 / 4;
    ca.s[4] = wm;   ca.d[4] = wm16;          ca.n4[4] = 65536 / 4;
    ca.s[5] = w1;   ca.d[5] = w1_16;         ca.n4[5] = 262144 / 4;
    ca.s[6] = w2;   ca.d[6] = w2_16;         ca.n4[6] = 131072 / 4;
    ca.total4 = (1048576 + 4 * 65536 + 262144 + 131072) / 4;
    cast_w_kernel<<<(ca.total4 + 255) / 256, 256, 0, stream>>>(ca);

    // 1. patch gather (bf16) + bf16 x into cat[:, 0:256]
    gather_kernel<<<2048, 256, 0, stream>>>(x, P16, cat);

    // 2. subsample conv GEMM, split-K=8 -> partials; fused reduce+bias+LN -> src16
    { dim3 g(2048 / BM, 256 / BN, 8);
      gemm_bf16<<<g, 256, 0, stream>>>(P16, 4096, srw16, 4096,
                                       partial, nullptr, 256, 512, 0, 2048l * 256); }
    ln_reduce_kernel<<<512, 256, 0, stream>>>(partial, sr_b, norm_g, norm_b, src16);

    // 3. fused K|V projection (N=512, act=3: elu+1 on K half), Q projection
    { dim3 g(2048 / BM, 512 / BN);
      gemm_bf16<<<g, 256, 0, stream>>>(src16, 256, wkv16, 256, nullptr, kv16, 512, 256, 3, 0); }
    { dim3 g(32768 / BM, 256 / BN);
      gemm_bf16<<<g, 256, 0, stream>>>(cat, 512, wq16, 256, nullptr, qbuf16, 256, 256, 1, 0); }

    // 4. linear attention
    kv_kernel<<<64, 256, 0, stream>>>(kv16, KV, Ksum);
    msg_kernel<<<512, 256, 0, stream>>>(qbuf16, KV, Ksum, msg16);

    // 5. merge proj (bf16 out) + LN(norm1) -> bf16 into cat[:, 256:512]
    { dim3 g(32768 / BM, 256 / BN);
      gemm_bf16<<<g, 256, 0, stream>>>(msg16, 256, wm16, 256, nullptr, merged16, 256, 256, 0, 0); }
    ln_kernel<<<8192, 256, 0, stream>>>(merged16, n1g, n1b, nullptr,
                                        nullptr, cat + 256, 512);

    // 6. concat-MLP: single K=512 GEMM (relu, bf16 out), then w2 GEMM (bf16 out)
    { dim3 g(32768 / BM, 512 / BN);
      gemm_bf16<<<g, 256, 0, stream>>>(cat, 512, w1_16, 512, nullptr, h1_16, 512, 512, 2, 0); }
    { dim3 g(32768 / BM, 256 / BN);
      gemm_bf16<<<g, 256, 0, stream>>>(h1_16, 512, w2_16, 512, nullptr, h2_16, 256, 512, 0, 0); }

    // 7. LN(norm2) + residual -> out (fp32)
    ln_kernel<<<8192, 256, 0, stream>>>(h2_16, n2g, n2b, x, out, nullptr, 256);
}

// Round 7
// 301.739 us; speedup vs baseline: 4.2696x; 1.0311x over previous
//
#include <hip/hip_runtime.h>
#include <hip/hip_bf16.h>
#include <math.h>

// Problem constants (fixed by the reference)
#define B_   8
#define N_   4096
#define C_   256
#define NH_  8
#define D_   32
#define S_   256      // (64/4)*(64/4)
#define HH_  64       // H = W = 64

#define BM 128
#define BN 128
#define BK 32

typedef __bf16 bf16x8 __attribute__((ext_vector_type(8)));
typedef float f32x4 __attribute__((ext_vector_type(4)));

__device__ inline ushort f2b(float f) {
    __hip_bfloat16 h = __float2bfloat16(f);
    return *reinterpret_cast<ushort*>(&h);
}
__device__ inline float b2f(ushort u) {
    unsigned v = (unsigned)u << 16;
    union { unsigned u; float f; } c; c.u = v; return c.f;
}

__device__ inline void gload16(const void* g, void* l) {
    __builtin_amdgcn_global_load_lds(
        (const __attribute__((address_space(1))) unsigned int*)g,
        (__attribute__((address_space(3))) unsigned int*)l, 16, 0, 0);
}

// ---------------------------------------------------------------------------
// Batched fp32 -> bf16 weight cast (one launch for all weight tensors)
// ---------------------------------------------------------------------------
#define NSEG 7
struct CastArgs {
    const float* s[NSEG];
    ushort*      d[NSEG];
    int          n4[NSEG];   // quads per segment
    int          total4;
};
__global__ __launch_bounds__(256) void cast_w_kernel(CastArgs a) {
    int idx = blockIdx.x * 256 + threadIdx.x;
    if (idx >= a.total4) return;
    int i = idx, s = 0;
    while (i >= a.n4[s]) { i -= a.n4[s]; ++s; }
    float4 f = ((const float4*)a.s[s])[i];
    ushort4 o;
    o.x = f2b(f.x); o.y = f2b(f.y); o.z = f2b(f.z); o.w = f2b(f.w);
    ((ushort4*)a.d[s])[i] = o;
}

// ---------------------------------------------------------------------------
// Gather 4x4xC patches -> P16[b*S+s][c*16+p*4+q] (bf16) AND write bf16 x into
// cat[:, 0:256] (cat is [32768][512] bf16, second half filled by norm1 later).
// ---------------------------------------------------------------------------
__global__ __launch_bounds__(256) void gather_kernel(const float* __restrict__ x,
                                                     ushort* __restrict__ P,
                                                     ushort* __restrict__ cat) {
    int bs = blockIdx.x;                 // b*256 + s
    int b = bs >> 8, s = bs & 255;
    int i = s >> 4, j = s & 15;
    int c = threadIdx.x;
    const float* xb = x + (size_t)b * N_ * C_;
    ushort u[16];
#pragma unroll
    for (int pq = 0; pq < 16; ++pq) {
        int p = pq >> 2, q = pq & 3;
        int n = (i * 4 + p) * HH_ + (j * 4 + q);
        float f = xb[(size_t)n * C_ + c];        // coalesced across c
        u[pq] = f2b(f);
        cat[((size_t)(b * N_ + n)) * 512 + c] = u[pq];   // coalesced across c
    }
    ushort* dst = P + (size_t)bs * 4096 + c * 16;
    ((uint4*)dst)[0] = *(uint4*)&u[0];
    ((uint4*)dst)[1] = *(uint4*)&u[8];
}

// ---------------------------------------------------------------------------
// bf16 MFMA GEMM (NT): C[m,n] = act( sum_k A[m,k] * W[n,k] )
// 128x128 tile, BK=32, 4 waves, 4x4 16x16x32 fragments per wave.
// T3 minimum 2-phase: LDS double-buffered; STAGE(t+1) issued BEFORE the
// ds_read+MFMA of tile t; ONE __syncthreads per K-step (its vmcnt(0) drain
// lands after ~300cy of compute instead of before it).
// Read-side XOR swizzle kept (source col pre-swizzled, same XOR on read).
// blockIdx.z = split-K slice (Kchunk each), writes Cf + z*spstride.
// act: 0 none, 1 elu(x)+1, 2 relu, 3 elu+1 if col<256 else none.
// Output: Cb (bf16) if non-null else Cf (fp32).
// ---------------------------------------------------------------------------
__global__ __launch_bounds__(256) void gemm_bf16(
    const ushort* __restrict__ A, int lda,
    const ushort* __restrict__ W, int ldw,
    float* __restrict__ Cf, ushort* __restrict__ Cb, int ldc,
    int Kchunk, int act, long spstride)
{
    __shared__ ushort As[2 * BM * BK];   // 2 x 8 KB (double-buffered)
    __shared__ ushort Bs[2 * BN * BK];
    const int t = threadIdx.x;
    const int lane = t & 63;
    const int w = t >> 6;
    const int wr = w >> 1, wc = w & 1;           // wave -> 64x64 quadrant
    const int fr = lane & 15, fq = lane >> 4;    // fragment row / k-group
    const int bm = blockIdx.x * BM, bn = blockIdx.y * BN;
    const long koff = (long)blockIdx.z * Kchunk;

    f32x4 acc[4][4] = {};

    const ushort* Ag = A + (size_t)bm * lda + koff;
    const ushort* Wg = W + (size_t)bn * ldw + koff;
    char* AsB = (char*)As;
    char* BsB = (char*)Bs;
    const int wuni = (t & ~63) * 16;             // wave-uniform LDS byte base

    // staging decomposition: chunk c = i*256+t -> row=c>>2, 16B col kb=(c&3)*8
    const int srow = t >> 2;
    const int skb0 = ((t & 3) * 8) ^ ((srow & 3) * 8);   // pre-swizzled source col

    auto STAGE = [&](int buf, int k0) {
#pragma unroll
        for (int i = 0; i < 2; ++i) {
            int row = i * 64 + srow;
            gload16(Ag + (size_t)row * lda + k0 + skb0, AsB + buf * 8192 + i * 4096 + wuni);
            gload16(Wg + (size_t)row * ldw + k0 + skb0, BsB + buf * 8192 + i * 4096 + wuni);
        }
    };

    STAGE(0, 0);
    __syncthreads();                 // drains vmcnt(0): buf0 ready
    int cur = 0;
    for (int k0 = 0; k0 < Kchunk; k0 += BK) {
        if (k0 + BK < Kchunk) STAGE(cur ^ 1, k0 + BK);   // prefetch next tile

        const ushort* Ac = As + cur * (BM * BK);
        const ushort* Bc = Bs + cur * (BN * BK);
        bf16x8 af[4], bv[4];
#pragma unroll
        for (int m = 0; m < 4; ++m) {
            int ra = wr * 64 + m * 16 + fr;
            af[m] = *(const bf16x8*)&Ac[ra * BK + (fq * 8 ^ ((ra & 3) * 8))];
        }
#pragma unroll
        for (int n = 0; n < 4; ++n) {
            int rb = wc * 64 + n * 16 + fr;
            bv[n] = *(const bf16x8*)&Bc[rb * BK + (fq * 8 ^ ((rb & 3) * 8))];
        }
#pragma unroll
        for (int m = 0; m < 4; ++m)
#pragma unroll
            for (int n = 0; n < 4; ++n)
                acc[m][n] = __builtin_amdgcn_mfma_f32_16x16x32_bf16(
                    af[m], bv[n], acc[m][n], 0, 0, 0);

        __syncthreads();             // one barrier/K-step: next buf ready, cur reusable
        cur ^= 1;
    }

    float* Cfz = Cf ? Cf + (size_t)blockIdx.z * spstride : nullptr;
#pragma unroll
    for (int m = 0; m < 4; ++m) {
#pragma unroll
        for (int n = 0; n < 4; ++n) {
            int col = bn + wc * 64 + n * 16 + fr;
#pragma unroll
            for (int i = 0; i < 4; ++i) {
                int row = bm + wr * 64 + m * 16 + fq * 4 + i;
                float v = acc[m][n][i];
                if (act == 1 || (act == 3 && col < 256))
                    v = v > 0.f ? v + 1.f : __expf(v);   // elu(x)+1
                else if (act == 2) v = fmaxf(v, 0.f);
                if (Cb) Cb[(size_t)row * ldc + col] = f2b(v);
                else    Cfz[(size_t)row * ldc + col] = v;
            }
        }
    }
}

// ---------------------------------------------------------------------------
// Sum 8 split-K partials + conv bias, then LayerNorm -> bf16 src.
// Wave-per-row: 4 rows/block, lane owns 4 cols, shfl_xor reduction.
// ---------------------------------------------------------------------------
__global__ __launch_bounds__(256) void ln_reduce_kernel(
    const float* __restrict__ part,     // [8][2048][256]
    const float* __restrict__ bias,
    const float* __restrict__ g, const float* __restrict__ bvec,
    ushort* __restrict__ outb)
{
    int row = blockIdx.x * 4 + (threadIdx.x >> 6);
    int lane = threadIdx.x & 63;
    int c0 = lane * 4;
    float4 v = *(const float4*)&bias[c0];
#pragma unroll
    for (int s = 0; s < 8; ++s) {
        float4 p = *(const float4*)&part[(size_t)s * 2048 * 256 + (size_t)row * 256 + c0];
        v.x += p.x; v.y += p.y; v.z += p.z; v.w += p.w;
    }
    float s1 = v.x + v.y + v.z + v.w;
    float s2 = v.x * v.x + v.y * v.y + v.z * v.z + v.w * v.w;
#pragma unroll
    for (int m = 1; m < 64; m <<= 1) {
        s1 += __shfl_xor(s1, m);
        s2 += __shfl_xor(s2, m);
    }
    float mean = s1 * (1.f / C_);
    float rstd = rsqrtf(s2 * (1.f / C_) - mean * mean + 1e-5f);
    float4 gv = *(const float4*)&g[c0];
    float4 bb = *(const float4*)&bvec[c0];
    ushort4 o;
    o.x = f2b((v.x - mean) * rstd * gv.x + bb.x);
    o.y = f2b((v.y - mean) * rstd * gv.y + bb.y);
    o.z = f2b((v.z - mean) * rstd * gv.z + bb.z);
    o.w = f2b((v.w - mean) * rstd * gv.w + bb.w);
    *(ushort4*)&outb[(size_t)row * C_ + c0] = o;
}

// ---------------------------------------------------------------------------
// LayerNorm over C=256, bf16 input. Wave-per-row (4 rows/block, no LDS).
// Optional fp32 residual. Output bf16 (outb, ld=ldout) or fp32 (outf).
// ---------------------------------------------------------------------------
__global__ __launch_bounds__(256) void ln_kernel(
    const ushort* __restrict__ inb,
    const float* __restrict__ g, const float* __restrict__ bvec,
    const float* __restrict__ residual,
    float* __restrict__ outf, ushort* __restrict__ outb, int ldout)
{
    int row = blockIdx.x * 4 + (threadIdx.x >> 6);
    int lane = threadIdx.x & 63;
    int c0 = lane * 4;
    ushort4 u = *(const ushort4*)&inb[(size_t)row * C_ + c0];
    float x0 = b2f(u.x), x1 = b2f(u.y), x2 = b2f(u.z), x3 = b2f(u.w);
    float s1 = x0 + x1 + x2 + x3;
    float s2 = x0 * x0 + x1 * x1 + x2 * x2 + x3 * x3;
#pragma unroll
    for (int m = 1; m < 64; m <<= 1) {
        s1 += __shfl_xor(s1, m);
        s2 += __shfl_xor(s2, m);
    }
    float mean = s1 * (1.f / C_);
    float rstd = rsqrtf(s2 * (1.f / C_) - mean * mean + 1e-5f);
    float4 gv = *(const float4*)&g[c0];
    float4 bb = *(const float4*)&bvec[c0];
    float y0 = (x0 - mean) * rstd * gv.x + bb.x;
    float y1 = (x1 - mean) * rstd * gv.y + bb.y;
    float y2 = (x2 - mean) * rstd * gv.z + bb.z;
    float y3 = (x3 - mean) * rstd * gv.w + bb.w;
    if (residual) {
        float4 r = *(const float4*)&residual[(size_t)row * C_ + c0];
        y0 += r.x; y1 += r.y; y2 += r.z; y3 += r.w;
    }
    if (outb) {
        ushort4 o; o.x = f2b(y0); o.y = f2b(y1); o.z = f2b(y2); o.w = f2b(y3);
        *(ushort4*)&outb[(size_t)row * ldout + c0] = o;
    } else {
        *(float4*)&outf[(size_t)row * ldout + c0] = make_float4(y0, y1, y2, y3);
    }
}

// ---------------------------------------------------------------------------
// Per (b,h): KV[d][v] = sum_s K[s,d]*V[s,v];  Ksum[d] = sum_s K[s,d]
// Input: fused kv16 [2048][512] bf16 (cols 0:256 = K heads, 256:512 = V heads)
// (reference /S on V and *S on msg cancel; Z uses unscaled Ksum)
// ---------------------------------------------------------------------------
__global__ __launch_bounds__(256) void kv_kernel(const ushort* __restrict__ kvin,
                                                 float* __restrict__ KV,
                                                 float* __restrict__ Ksum) {
    int bh = blockIdx.x;
    int b = bh >> 3, h = bh & 7;
    const ushort* Kp = kvin + (size_t)b * S_ * 512 + h * D_;
    const ushort* Vp = Kp + 256;
    int tid = threadIdx.x;
    __shared__ float Ks[8][32], Vs[8][32];
    int d = tid >> 3, vq = tid & 7;
    int ls = tid >> 5, lc = tid & 31;
    float acc[4] = {0.f, 0.f, 0.f, 0.f};
    float ks = 0.f;
    for (int s0 = 0; s0 < S_; s0 += 8) {
        __syncthreads();
        Ks[ls][lc] = b2f(Kp[(size_t)(s0 + ls) * 512 + lc]);
        Vs[ls][lc] = b2f(Vp[(size_t)(s0 + ls) * 512 + lc]);
        __syncthreads();
#pragma unroll
        for (int ss = 0; ss < 8; ++ss) {
            float kd = Ks[ss][d];
            if (vq == 0) ks += kd;
#pragma unroll
            for (int jj = 0; jj < 4; ++jj)
                acc[jj] += kd * Vs[ss][vq * 4 + jj];
        }
    }
    float* kvout = KV + ((size_t)bh * 32 + d) * 32 + vq * 4;
#pragma unroll
    for (int jj = 0; jj < 4; ++jj) kvout[jj] = acc[jj];
    if (vq == 0) Ksum[bh * 32 + d] = ks;
}

// ---------------------------------------------------------------------------
// msg[row, h*32+v] = (Q·KV[h,:,v]) / (Q·Ksum[h] + eps), Q bf16.
// Block = 64 rows of one b. KV+Ksum staged LDS once -> per-thread registers
// (fixed h,v per thread). Q rows streamed through LDS 8 at a time.
// ---------------------------------------------------------------------------
__global__ __launch_bounds__(256) void msg_kernel(const ushort* __restrict__ Q,
                                                  const float* __restrict__ KV,
                                                  const float* __restrict__ Ksum,
                                                  ushort* __restrict__ out) {
    const int row0 = blockIdx.x * 64;        // 4096 % 64 == 0: never crosses b
    const int b = row0 >> 12;
    const int tid = threadIdx.x;
    const int h = tid >> 5, v = tid & 31;
    __shared__ float KVs[8192];              // [h][d][v]  32 KB
    __shared__ float Kss[256];               // [h][d]      1 KB
    __shared__ ushort Qs[8][256];            //             4 KB
    const float4* kvsrc = (const float4*)(KV + (size_t)b * 8192);
#pragma unroll
    for (int i = 0; i < 8; ++i)
        ((float4*)KVs)[i * 256 + tid] = kvsrc[i * 256 + tid];
    if (tid < 64)
        ((float4*)Kss)[tid] = ((const float4*)(Ksum + b * 256))[tid];
    __syncthreads();
    float kvr[32], ksr[32];                  // this thread's KV column / Ksum row
#pragma unroll
    for (int d = 0; d < 32; ++d) {
        kvr[d] = KVs[h * 1024 + d * 32 + v];
        ksr[d] = Kss[h * 32 + d];
    }
    for (int r0 = 0; r0 < 64; r0 += 8) {
        __syncthreads();
        { int r = tid >> 5, c8 = (tid & 31) * 8;
          *(uint4*)&Qs[r][c8] = *(const uint4*)&Q[(size_t)(row0 + r0 + r) * 256 + c8]; }
        __syncthreads();
#pragma unroll
        for (int r = 0; r < 8; ++r) {
            ushort q[32];
            *(uint4*)&q[0]  = *(const uint4*)&Qs[r][h * 32 + 0];
            *(uint4*)&q[8]  = *(const uint4*)&Qs[r][h * 32 + 8];
            *(uint4*)&q[16] = *(const uint4*)&Qs[r][h * 32 + 16];
            *(uint4*)&q[24] = *(const uint4*)&Qs[r][h * 32 + 24];
            float z = 1e-6f, m = 0.f;
#pragma unroll
            for (int d = 0; d < 32; ++d) {
                float qd = b2f(q[d]);
                z = fmaf(qd, ksr[d], z);
                m = fmaf(qd, kvr[d], m);
            }
            out[(size_t)(row0 + r0 + r) * 256 + tid] = f2b(m / z);
        }
    }
}

// ---------------------------------------------------------------------------
extern "C" void kernel_launch(void* const* d_in, const int* in_sizes, int n_in,
                              void* d_out, int out_size, void* d_ws, size_t ws_size,
                              hipStream_t stream) {
    const float* x      = (const float*)d_in[0];
    const float* sr_w   = (const float*)d_in[1];   // [256,4096] OIHW flat
    const float* sr_b   = (const float*)d_in[2];
    const float* norm_g = (const float*)d_in[3];
    const float* norm_b = (const float*)d_in[4];
    const float* wq     = (const float*)d_in[5];
    const float* wk     = (const float*)d_in[6];
    const float* wv     = (const float*)d_in[7];
    const float* wm     = (const float*)d_in[8];
    const float* w1     = (const float*)d_in[9];   // [512,512]
    const float* w2     = (const float*)d_in[10];  // [256,512]
    const float* n1g    = (const float*)d_in[11];
    const float* n1b    = (const float*)d_in[12];
    const float* n2g    = (const float*)d_in[13];
    const float* n2b    = (const float*)d_in[14];
    float* out = (float*)d_out;

    char* base = (char*)d_ws;
    size_t off = 0;
    auto alloc = [&](size_t bytes) {
        char* p = base + off;
        off += (bytes + 1023) & ~(size_t)1023;
        return p;
    };
    ushort* P16      = (ushort*)alloc(2048ull * 4096 * 2);       // 16.8 MB
    float*  partial  = (float*) alloc(8ull * 2048 * 256 * 4);    // 16.8 MB
    ushort* cat      = (ushort*)alloc(32768ull * 512 * 2);       // 33.6 MB
    ushort* src16    = (ushort*)alloc(2048ull * 256 * 2);
    ushort* kv16     = (ushort*)alloc(2048ull * 512 * 2);        // 2.1 MB
    ushort* qbuf16   = (ushort*)alloc(32768ull * 256 * 2);       // 16.8 MB
    ushort* msg16    = (ushort*)alloc(32768ull * 256 * 2);       // 16.8 MB
    ushort* merged16 = (ushort*)alloc(32768ull * 256 * 2);       // 16.8 MB
    ushort* h1_16    = (ushort*)alloc(32768ull * 512 * 2);       // 33.6 MB
    float*  KV       = (float*) alloc(64ull * 32 * 32 * 4);
    float*  Ksum     = (float*) alloc(64ull * 32 * 4);
    ushort* srw16    = (ushort*)alloc(1048576ull * 2);
    ushort* wq16     = (ushort*)alloc(65536ull * 2);
    ushort* wkv16    = (ushort*)alloc(131072ull * 2);            // [wk;wv] stacked
    ushort* wm16     = (ushort*)alloc(65536ull * 2);
    ushort* w1_16    = (ushort*)alloc(262144ull * 2);
    ushort* w2_16    = (ushort*)alloc(131072ull * 2);
    // dead-buffer reuse: P16 (+partial) dead after ln_reduce -> h2 bf16 lives there
    ushort* h2_16 = P16;

    // 0. cast all weights to bf16 in one launch (wk,wv -> stacked wkv16)
    CastArgs ca;
    ca.s[0] = sr_w; ca.d[0] = srw16;         ca.n4[0] = 1048576 / 4;
    ca.s[1] = wq;   ca.d[1] = wq16;          ca.n4[1] = 65536 / 4;
    ca.s[2] = wk;   ca.d[2] = wkv16;         ca.n4[2] = 65536 / 4;
    ca.s[3] = wv;   ca.d[3] = wkv16 + 65536; ca.n4[3] = 65536 / 4;
    ca.s[4] = wm;   ca.d[4] = wm16;          ca.n4[4] = 65536 / 4;
    ca.s[5] = w1;   ca.d[5] = w1_16;         ca.n4[5] = 262144 / 4;
    ca.s[6] = w2;   ca.d[6] = w2_16;         ca.n4[6] = 131072 / 4;
    ca.total4 = (1048576 + 4 * 65536 + 262144 + 131072) / 4;
    cast_w_kernel<<<(ca.total4 + 255) / 256, 256, 0, stream>>>(ca);

    // 1. patch gather (bf16) + bf16 x into cat[:, 0:256]
    gather_kernel<<<2048, 256, 0, stream>>>(x, P16, cat);

    // 2. subsample conv GEMM, split-K=8 -> partials; fused reduce+bias+LN -> src16
    { dim3 g(2048 / BM, 256 / BN, 8);
      gemm_bf16<<<g, 256, 0, stream>>>(P16, 4096, srw16, 4096,
                                       partial, nullptr, 256, 512, 0, 2048l * 256); }
    ln_reduce_kernel<<<512, 256, 0, stream>>>(partial, sr_b, norm_g, norm_b, src16);

    // 3. fused K|V projection (N=512, act=3: elu+1 on K half), Q projection
    { dim3 g(2048 / BM, 512 / BN);
      gemm_bf16<<<g, 256, 0, stream>>>(src16, 256, wkv16, 256, nullptr, kv16, 512, 256, 3, 0); }
    { dim3 g(32768 / BM, 256 / BN);
      gemm_bf16<<<g, 256, 0, stream>>>(cat, 512, wq16, 256, nullptr, qbuf16, 256, 256, 1, 0); }

    // 4. linear attention
    kv_kernel<<<64, 256, 0, stream>>>(kv16, KV, Ksum);
    msg_kernel<<<512, 256, 0, stream>>>(qbuf16, KV, Ksum, msg16);

    // 5. merge proj (bf16 out) + LN(norm1) -> bf16 into cat[:, 256:512]
    { dim3 g(32768 / BM, 256 / BN);
      gemm_bf16<<<g, 256, 0, stream>>>(msg16, 256, wm16, 256, nullptr, merged16, 256, 256, 0, 0); }
    ln_kernel<<<8192, 256, 0, stream>>>(merged16, n1g, n1b, nullptr,
                                        nullptr, cat + 256, 512);

    // 6. concat-MLP: single K=512 GEMM (relu, bf16 out), then w2 GEMM (bf16 out)
    { dim3 g(32768 / BM, 512 / BN);
      gemm_bf16<<<g, 256, 0, stream>>>(cat, 512, w1_16, 512, nullptr, h1_16, 512, 512, 2, 0); }
    { dim3 g(32768 / BM, 256 / BN);
      gemm_bf16<<<g, 256, 0, stream>>>(h1_16, 512, w2_16, 512, nullptr, h2_16, 256, 512, 0, 0); }

    // 7. LN(norm2) + residual -> out (fp32)
    ln_kernel<<<8192, 256, 0, stream>>>(h2_16, n2g, n2b, x, out, nullptr, 256);
}

// Round 8
// 279.337 us; speedup vs baseline: 4.6120x; 1.0802x over previous
//
#include <hip/hip_runtime.h>
#include <hip/hip_bf16.h>
#include <math.h>

// Problem constants (fixed by the reference)
#define B_   8
#define N_   4096
#define C_   256
#define NH_  8
#define D_   32
#define S_   256      // (64/4)*(64/4)
#define HH_  64       // H = W = 64

#define BM 128
#define BN 128
#define BK 32
#define NSLICE 16     // conv split-K slices

typedef __bf16 bf16x8 __attribute__((ext_vector_type(8)));
typedef float f32x4 __attribute__((ext_vector_type(4)));

__device__ inline ushort f2b(float f) {
    __hip_bfloat16 h = __float2bfloat16(f);
    return *reinterpret_cast<ushort*>(&h);
}
__device__ inline float b2f(ushort u) {
    unsigned v = (unsigned)u << 16;
    union { unsigned u; float f; } c; c.u = v; return c.f;
}

__device__ inline void gload16(const void* g, void* l) {
    __builtin_amdgcn_global_load_lds(
        (const __attribute__((address_space(1))) unsigned int*)g,
        (__attribute__((address_space(3))) unsigned int*)l, 16, 0, 0);
}

// ---------------------------------------------------------------------------
// Batched fp32 -> bf16 weight cast (one launch for all weight tensors)
// ---------------------------------------------------------------------------
#define NSEG 7
struct CastArgs {
    const float* s[NSEG];
    ushort*      d[NSEG];
    int          n4[NSEG];   // quads per segment
    int          total4;
};
__global__ __launch_bounds__(256) void cast_w_kernel(CastArgs a) {
    int idx = blockIdx.x * 256 + threadIdx.x;
    if (idx >= a.total4) return;
    int i = idx, s = 0;
    while (i >= a.n4[s]) { i -= a.n4[s]; ++s; }
    float4 f = ((const float4*)a.s[s])[i];
    ushort4 o;
    o.x = f2b(f.x); o.y = f2b(f.y); o.z = f2b(f.z); o.w = f2b(f.w);
    ((ushort4*)a.d[s])[i] = o;
}

// ---------------------------------------------------------------------------
// Gather 4x4xC patches -> P16[b*S+s][c*16+p*4+q] (bf16) AND write bf16 x into
// cat[:, 0:256] (cat is [32768][512] bf16, second half filled by norm1 later).
// ---------------------------------------------------------------------------
__global__ __launch_bounds__(256) void gather_kernel(const float* __restrict__ x,
                                                     ushort* __restrict__ P,
                                                     ushort* __restrict__ cat) {
    int bs = blockIdx.x;                 // b*256 + s
    int b = bs >> 8, s = bs & 255;
    int i = s >> 4, j = s & 15;
    int c = threadIdx.x;
    const float* xb = x + (size_t)b * N_ * C_;
    ushort u[16];
#pragma unroll
    for (int pq = 0; pq < 16; ++pq) {
        int p = pq >> 2, q = pq & 3;
        int n = (i * 4 + p) * HH_ + (j * 4 + q);
        float f = xb[(size_t)n * C_ + c];        // coalesced across c
        u[pq] = f2b(f);
        cat[((size_t)(b * N_ + n)) * 512 + c] = u[pq];   // coalesced across c
    }
    ushort* dst = P + (size_t)bs * 4096 + c * 16;
    ((uint4*)dst)[0] = *(uint4*)&u[0];
    ((uint4*)dst)[1] = *(uint4*)&u[8];
}

// ---------------------------------------------------------------------------
// bf16 MFMA GEMM (NT): C[m,n] = act( sum_k A[m,k] * W[n,k] )
// 128x128 tile, BK=32, **8 waves (512 thr)**, wave-tile 64x32, acc 4x2.
// TLP-first: 32 KB LDS x 4 blocks/CU = up to 32 waves/CU to hide the
// staging drain (R6/R7 showed 2-phase dbuf alone leaves MfmaUtil ~14% at
// ~6 waves/CU). 2-phase dbuf kept; read-side XOR swizzle kept.
// Staging: exactly 1 A-load + 1 B-load (16B) per thread per K-step.
// blockIdx.z = split-K slice (Kchunk each), writes Cf + z*spstride.
// act: 0 none, 1 elu(x)+1, 2 relu, 3 elu+1 if col<256 else none.
// Output: Cb (bf16) if non-null else Cf (fp32).
// ---------------------------------------------------------------------------
__global__ __launch_bounds__(512) void gemm_bf16(
    const ushort* __restrict__ A, int lda,
    const ushort* __restrict__ W, int ldw,
    float* __restrict__ Cf, ushort* __restrict__ Cb, int ldc,
    int Kchunk, int act, long spstride)
{
    __shared__ ushort As[2 * BM * BK];   // 2 x 8 KB (double-buffered)
    __shared__ ushort Bs[2 * BN * BK];
    const int t = threadIdx.x;
    const int lane = t & 63;
    const int w = t >> 6;                        // 0..7
    const int wr = w >> 2, wc = w & 3;           // 2 row-groups x 4 col-groups
    const int fr = lane & 15, fq = lane >> 4;    // fragment row / k-group
    const int bm = blockIdx.x * BM, bn = blockIdx.y * BN;
    const long koff = (long)blockIdx.z * Kchunk;

    f32x4 acc[4][2] = {};

    const ushort* Ag = A + (size_t)bm * lda + koff;
    const ushort* Wg = W + (size_t)bn * ldw + koff;
    char* AsB = (char*)As;
    char* BsB = (char*)Bs;
    const int wuni = (t & ~63) * 16;             // wave-uniform LDS byte base

    // staging: thread t covers row srow=t>>2, 16B chunk (t&3); source col
    // pre-swizzled so linear LDS + swizzled read = bank-conflict-free.
    const int srow = t >> 2;                     // 0..127
    const int skb0 = ((t & 3) * 8) ^ ((srow & 3) * 8);

    auto STAGE = [&](int buf, int k0) {
        gload16(Ag + (size_t)srow * lda + k0 + skb0, AsB + buf * 8192 + wuni);
        gload16(Wg + (size_t)srow * ldw + k0 + skb0, BsB + buf * 8192 + wuni);
    };

    STAGE(0, 0);
    __syncthreads();                 // drains vmcnt(0): buf0 ready
    int cur = 0;
    for (int k0 = 0; k0 < Kchunk; k0 += BK) {
        if (k0 + BK < Kchunk) STAGE(cur ^ 1, k0 + BK);   // prefetch next tile

        const ushort* Ac = As + cur * (BM * BK);
        const ushort* Bc = Bs + cur * (BN * BK);
        bf16x8 af[4], bv[2];
#pragma unroll
        for (int m = 0; m < 4; ++m) {
            int ra = wr * 64 + m * 16 + fr;
            af[m] = *(const bf16x8*)&Ac[ra * BK + (fq * 8 ^ ((ra & 3) * 8))];
        }
#pragma unroll
        for (int n = 0; n < 2; ++n) {
            int rb = wc * 32 + n * 16 + fr;
            bv[n] = *(const bf16x8*)&Bc[rb * BK + (fq * 8 ^ ((rb & 3) * 8))];
        }
#pragma unroll
        for (int m = 0; m < 4; ++m)
#pragma unroll
            for (int n = 0; n < 2; ++n)
                acc[m][n] = __builtin_amdgcn_mfma_f32_16x16x32_bf16(
                    af[m], bv[n], acc[m][n], 0, 0, 0);

        __syncthreads();             // one barrier/K-step: next buf ready, cur reusable
        cur ^= 1;
    }

    float* Cfz = Cf ? Cf + (size_t)blockIdx.z * spstride : nullptr;
#pragma unroll
    for (int m = 0; m < 4; ++m) {
#pragma unroll
        for (int n = 0; n < 2; ++n) {
            int col = bn + wc * 32 + n * 16 + fr;
#pragma unroll
            for (int i = 0; i < 4; ++i) {
                int row = bm + wr * 64 + m * 16 + fq * 4 + i;
                float v = acc[m][n][i];
                if (act == 1 || (act == 3 && col < 256))
                    v = v > 0.f ? v + 1.f : __expf(v);   // elu(x)+1
                else if (act == 2) v = fmaxf(v, 0.f);
                if (Cb) Cb[(size_t)row * ldc + col] = f2b(v);
                else    Cfz[(size_t)row * ldc + col] = v;
            }
        }
    }
}

// ---------------------------------------------------------------------------
// Sum NSLICE split-K partials + conv bias, then LayerNorm -> bf16 src.
// Wave-per-row: 4 rows/block, lane owns 4 cols, shfl_xor reduction.
// ---------------------------------------------------------------------------
__global__ __launch_bounds__(256) void ln_reduce_kernel(
    const float* __restrict__ part,     // [NSLICE][2048][256]
    const float* __restrict__ bias,
    const float* __restrict__ g, const float* __restrict__ bvec,
    ushort* __restrict__ outb)
{
    int row = blockIdx.x * 4 + (threadIdx.x >> 6);
    int lane = threadIdx.x & 63;
    int c0 = lane * 4;
    float4 v = *(const float4*)&bias[c0];
#pragma unroll
    for (int s = 0; s < NSLICE; ++s) {
        float4 p = *(const float4*)&part[(size_t)s * 2048 * 256 + (size_t)row * 256 + c0];
        v.x += p.x; v.y += p.y; v.z += p.z; v.w += p.w;
    }
    float s1 = v.x + v.y + v.z + v.w;
    float s2 = v.x * v.x + v.y * v.y + v.z * v.z + v.w * v.w;
#pragma unroll
    for (int m = 1; m < 64; m <<= 1) {
        s1 += __shfl_xor(s1, m);
        s2 += __shfl_xor(s2, m);
    }
    float mean = s1 * (1.f / C_);
    float rstd = rsqrtf(s2 * (1.f / C_) - mean * mean + 1e-5f);
    float4 gv = *(const float4*)&g[c0];
    float4 bb = *(const float4*)&bvec[c0];
    ushort4 o;
    o.x = f2b((v.x - mean) * rstd * gv.x + bb.x);
    o.y = f2b((v.y - mean) * rstd * gv.y + bb.y);
    o.z = f2b((v.z - mean) * rstd * gv.z + bb.z);
    o.w = f2b((v.w - mean) * rstd * gv.w + bb.w);
    *(ushort4*)&outb[(size_t)row * C_ + c0] = o;
}

// ---------------------------------------------------------------------------
// LayerNorm over C=256, bf16 input. Wave-per-row (4 rows/block, no LDS).
// Optional fp32 residual. Output bf16 (outb, ld=ldout) or fp32 (outf).
// ---------------------------------------------------------------------------
__global__ __launch_bounds__(256) void ln_kernel(
    const ushort* __restrict__ inb,
    const float* __restrict__ g, const float* __restrict__ bvec,
    const float* __restrict__ residual,
    float* __restrict__ outf, ushort* __restrict__ outb, int ldout)
{
    int row = blockIdx.x * 4 + (threadIdx.x >> 6);
    int lane = threadIdx.x & 63;
    int c0 = lane * 4;
    ushort4 u = *(const ushort4*)&inb[(size_t)row * C_ + c0];
    float x0 = b2f(u.x), x1 = b2f(u.y), x2 = b2f(u.z), x3 = b2f(u.w);
    float s1 = x0 + x1 + x2 + x3;
    float s2 = x0 * x0 + x1 * x1 + x2 * x2 + x3 * x3;
#pragma unroll
    for (int m = 1; m < 64; m <<= 1) {
        s1 += __shfl_xor(s1, m);
        s2 += __shfl_xor(s2, m);
    }
    float mean = s1 * (1.f / C_);
    float rstd = rsqrtf(s2 * (1.f / C_) - mean * mean + 1e-5f);
    float4 gv = *(const float4*)&g[c0];
    float4 bb = *(const float4*)&bvec[c0];
    float y0 = (x0 - mean) * rstd * gv.x + bb.x;
    float y1 = (x1 - mean) * rstd * gv.y + bb.y;
    float y2 = (x2 - mean) * rstd * gv.z + bb.z;
    float y3 = (x3 - mean) * rstd * gv.w + bb.w;
    if (residual) {
        float4 r = *(const float4*)&residual[(size_t)row * C_ + c0];
        y0 += r.x; y1 += r.y; y2 += r.z; y3 += r.w;
    }
    if (outb) {
        ushort4 o; o.x = f2b(y0); o.y = f2b(y1); o.z = f2b(y2); o.w = f2b(y3);
        *(ushort4*)&outb[(size_t)row * ldout + c0] = o;
    } else {
        *(float4*)&outf[(size_t)row * ldout + c0] = make_float4(y0, y1, y2, y3);
    }
}

// ---------------------------------------------------------------------------
// Per (b,h): KV[d][v] = sum_s K[s,d]*V[s,v];  Ksum[d] = sum_s K[s,d]
// Input: fused kv16 [2048][512] bf16 (cols 0:256 = K heads, 256:512 = V heads)
// (reference /S on V and *S on msg cancel; Z uses unscaled Ksum)
// ---------------------------------------------------------------------------
__global__ __launch_bounds__(256) void kv_kernel(const ushort* __restrict__ kvin,
                                                 float* __restrict__ KV,
                                                 float* __restrict__ Ksum) {
    int bh = blockIdx.x;
    int b = bh >> 3, h = bh & 7;
    const ushort* Kp = kvin + (size_t)b * S_ * 512 + h * D_;
    const ushort* Vp = Kp + 256;
    int tid = threadIdx.x;
    __shared__ float Ks[8][32], Vs[8][32];
    int d = tid >> 3, vq = tid & 7;
    int ls = tid >> 5, lc = tid & 31;
    float acc[4] = {0.f, 0.f, 0.f, 0.f};
    float ks = 0.f;
    for (int s0 = 0; s0 < S_; s0 += 8) {
        __syncthreads();
        Ks[ls][lc] = b2f(Kp[(size_t)(s0 + ls) * 512 + lc]);
        Vs[ls][lc] = b2f(Vp[(size_t)(s0 + ls) * 512 + lc]);
        __syncthreads();
#pragma unroll
        for (int ss = 0; ss < 8; ++ss) {
            float kd = Ks[ss][d];
            if (vq == 0) ks += kd;
#pragma unroll
            for (int jj = 0; jj < 4; ++jj)
                acc[jj] += kd * Vs[ss][vq * 4 + jj];
        }
    }
    float* kvout = KV + ((size_t)bh * 32 + d) * 32 + vq * 4;
#pragma unroll
    for (int jj = 0; jj < 4; ++jj) kvout[jj] = acc[jj];
    if (vq == 0) Ksum[bh * 32 + d] = ks;
}

// ---------------------------------------------------------------------------
// msg[row, h*32+v] = (Q·KV[h,:,v]) / (Q·Ksum[h] + eps), Q bf16.
// Block = 64 rows of one b. KV+Ksum staged LDS once -> per-thread registers
// (fixed h,v per thread). Q rows streamed through LDS 8 at a time.
// ---------------------------------------------------------------------------
__global__ __launch_bounds__(256) void msg_kernel(const ushort* __restrict__ Q,
                                                  const float* __restrict__ KV,
                                                  const float* __restrict__ Ksum,
                                                  ushort* __restrict__ out) {
    const int row0 = blockIdx.x * 64;        // 4096 % 64 == 0: never crosses b
    const int b = row0 >> 12;
    const int tid = threadIdx.x;
    const int h = tid >> 5, v = tid & 31;
    __shared__ float KVs[8192];              // [h][d][v]  32 KB
    __shared__ float Kss[256];               // [h][d]      1 KB
    __shared__ ushort Qs[8][256];            //             4 KB
    const float4* kvsrc = (const float4*)(KV + (size_t)b * 8192);
#pragma unroll
    for (int i = 0; i < 8; ++i)
        ((float4*)KVs)[i * 256 + tid] = kvsrc[i * 256 + tid];
    if (tid < 64)
        ((float4*)Kss)[tid] = ((const float4*)(Ksum + b * 256))[tid];
    __syncthreads();
    float kvr[32], ksr[32];                  // this thread's KV column / Ksum row
#pragma unroll
    for (int d = 0; d < 32; ++d) {
        kvr[d] = KVs[h * 1024 + d * 32 + v];
        ksr[d] = Kss[h * 32 + d];
    }
    for (int r0 = 0; r0 < 64; r0 += 8) {
        __syncthreads();
        { int r = tid >> 5, c8 = (tid & 31) * 8;
          *(uint4*)&Qs[r][c8] = *(const uint4*)&Q[(size_t)(row0 + r0 + r) * 256 + c8]; }
        __syncthreads();
#pragma unroll
        for (int r = 0; r < 8; ++r) {
            ushort q[32];
            *(uint4*)&q[0]  = *(const uint4*)&Qs[r][h * 32 + 0];
            *(uint4*)&q[8]  = *(const uint4*)&Qs[r][h * 32 + 8];
            *(uint4*)&q[16] = *(const uint4*)&Qs[r][h * 32 + 16];
            *(uint4*)&q[24] = *(const uint4*)&Qs[r][h * 32 + 24];
            float z = 1e-6f, m = 0.f;
#pragma unroll
            for (int d = 0; d < 32; ++d) {
                float qd = b2f(q[d]);
                z = fmaf(qd, ksr[d], z);
                m = fmaf(qd, kvr[d], m);
            }
            out[(size_t)(row0 + r0 + r) * 256 + tid] = f2b(m / z);
        }
    }
}

// ---------------------------------------------------------------------------
extern "C" void kernel_launch(void* const* d_in, const int* in_sizes, int n_in,
                              void* d_out, int out_size, void* d_ws, size_t ws_size,
                              hipStream_t stream) {
    const float* x      = (const float*)d_in[0];
    const float* sr_w   = (const float*)d_in[1];   // [256,4096] OIHW flat
    const float* sr_b   = (const float*)d_in[2];
    const float* norm_g = (const float*)d_in[3];
    const float* norm_b = (const float*)d_in[4];
    const float* wq     = (const float*)d_in[5];
    const float* wk     = (const float*)d_in[6];
    const float* wv     = (const float*)d_in[7];
    const float* wm     = (const float*)d_in[8];
    const float* w1     = (const float*)d_in[9];   // [512,512]
    const float* w2     = (const float*)d_in[10];  // [256,512]
    const float* n1g    = (const float*)d_in[11];
    const float* n1b    = (const float*)d_in[12];
    const float* n2g    = (const float*)d_in[13];
    const float* n2b    = (const float*)d_in[14];
    float* out = (float*)d_out;

    char* base = (char*)d_ws;
    size_t off = 0;
    auto alloc = [&](size_t bytes) {
        char* p = base + off;
        off += (bytes + 1023) & ~(size_t)1023;
        return p;
    };
    ushort* P16      = (ushort*)alloc(2048ull * 4096 * 2);          // 16.8 MB
    float*  partial  = (float*) alloc((size_t)NSLICE * 2048 * 256 * 4);  // 33.6 MB
    ushort* cat      = (ushort*)alloc(32768ull * 512 * 2);          // 33.6 MB
    ushort* src16    = (ushort*)alloc(2048ull * 256 * 2);
    ushort* kv16     = (ushort*)alloc(2048ull * 512 * 2);           // 2.1 MB
    ushort* qbuf16   = (ushort*)alloc(32768ull * 256 * 2);          // 16.8 MB
    ushort* msg16    = (ushort*)alloc(32768ull * 256 * 2);          // 16.8 MB
    ushort* merged16 = (ushort*)alloc(32768ull * 256 * 2);          // 16.8 MB
    ushort* h1_16    = (ushort*)alloc(32768ull * 512 * 2);          // 33.6 MB
    float*  KV       = (float*) alloc(64ull * 32 * 32 * 4);
    float*  Ksum     = (float*) alloc(64ull * 32 * 4);
    ushort* srw16    = (ushort*)alloc(1048576ull * 2);
    ushort* wq16     = (ushort*)alloc(65536ull * 2);
    ushort* wkv16    = (ushort*)alloc(131072ull * 2);               // [wk;wv] stacked
    ushort* wm16     = (ushort*)alloc(65536ull * 2);
    ushort* w1_16    = (ushort*)alloc(262144ull * 2);
    ushort* w2_16    = (ushort*)alloc(131072ull * 2);
    // dead-buffer reuse: P16 dead after conv gemm -> h2 bf16 lives there
    ushort* h2_16 = P16;

    // 0. cast all weights to bf16 in one launch (wk,wv -> stacked wkv16)
    CastArgs ca;
    ca.s[0] = sr_w; ca.d[0] = srw16;         ca.n4[0] = 1048576 / 4;
    ca.s[1] = wq;   ca.d[1] = wq16;          ca.n4[1] = 65536 / 4;
    ca.s[2] = wk;   ca.d[2] = wkv16;         ca.n4[2] = 65536 / 4;
    ca.s[3] = wv;   ca.d[3] = wkv16 + 65536; ca.n4[3] = 65536 / 4;
    ca.s[4] = wm;   ca.d[4] = wm16;          ca.n4[4] = 65536 / 4;
    ca.s[5] = w1;   ca.d[5] = w1_16;         ca.n4[5] = 262144 / 4;
    ca.s[6] = w2;   ca.d[6] = w2_16;         ca.n4[6] = 131072 / 4;
    ca.total4 = (1048576 + 4 * 65536 + 262144 + 131072) / 4;
    cast_w_kernel<<<(ca.total4 + 255) / 256, 256, 0, stream>>>(ca);

    // 1. patch gather (bf16) + bf16 x into cat[:, 0:256]
    gather_kernel<<<2048, 256, 0, stream>>>(x, P16, cat);

    // 2. subsample conv GEMM, split-K=16 -> partials; fused reduce+bias+LN -> src16
    { dim3 g(2048 / BM, 256 / BN, NSLICE);
      gemm_bf16<<<g, 512, 0, stream>>>(P16, 4096, srw16, 4096,
                                       partial, nullptr, 256, 4096 / NSLICE, 0, 2048l * 256); }
    ln_reduce_kernel<<<512, 256, 0, stream>>>(partial, sr_b, norm_g, norm_b, src16);

    // 3. fused K|V projection (N=512, act=3: elu+1 on K half), Q projection
    { dim3 g(2048 / BM, 512 / BN);
      gemm_bf16<<<g, 512, 0, stream>>>(src16, 256, wkv16, 256, nullptr, kv16, 512, 256, 3, 0); }
    { dim3 g(32768 / BM, 256 / BN);
      gemm_bf16<<<g, 512, 0, stream>>>(cat, 512, wq16, 256, nullptr, qbuf16, 256, 256, 1, 0); }

    // 4. linear attention
    kv_kernel<<<64, 256, 0, stream>>>(kv16, KV, Ksum);
    msg_kernel<<<512, 256, 0, stream>>>(qbuf16, KV, Ksum, msg16);

    // 5. merge proj (bf16 out) + LN(norm1) -> bf16 into cat[:, 256:512]
    { dim3 g(32768 / BM, 256 / BN);
      gemm_bf16<<<g, 512, 0, stream>>>(msg16, 256, wm16, 256, nullptr, merged16, 256, 256, 0, 0); }
    ln_kernel<<<8192, 256, 0, stream>>>(merged16, n1g, n1b, nullptr,
                                        nullptr, cat + 256, 512);

    // 6. concat-MLP: single K=512 GEMM (relu, bf16 out), then w2 GEMM (bf16 out)
    { dim3 g(32768 / BM, 512 / BN);
      gemm_bf16<<<g, 512, 0, stream>>>(cat, 512, w1_16, 512, nullptr, h1_16, 512, 512, 2, 0); }
    { dim3 g(32768 / BM, 256 / BN);
      gemm_bf16<<<g, 512, 0, stream>>>(h1_16, 512, w2_16, 512, nullptr, h2_16, 256, 512, 0, 0); }

    // 7. LN(norm2) + residual -> out (fp32)
    ln_kernel<<<8192, 256, 0, stream>>>(h2_16, n2g, n2b, x, out, nullptr, 256);
}

// Round 10
// 276.972 us; speedup vs baseline: 4.6514x; 1.0085x over previous
//
#include <hip/hip_runtime.h>
#include <hip/hip_bf16.h>
#include <math.h>

// Problem constants (fixed by the reference)
#define B_   8
#define N_   4096
#define C_   256
#define NH_  8
#define D_   32
#define S_   256      // (64/4)*(64/4)
#define HH_  64       // H = W = 64

#define BM 128
#define BN 128
#define BK 32
#define NSLICE 16     // conv split-K slices

typedef __bf16 bf16x8 __attribute__((ext_vector_type(8)));
typedef float f32x4 __attribute__((ext_vector_type(4)));

__device__ inline ushort f2b(float f) {
    __hip_bfloat16 h = __float2bfloat16(f);
    return *reinterpret_cast<ushort*>(&h);
}
__device__ inline float b2f(ushort u) {
    unsigned v = (unsigned)u << 16;
    union { unsigned u; float f; } c; c.u = v; return c.f;
}

__device__ inline void gload16(const void* g, void* l) {
    __builtin_amdgcn_global_load_lds(
        (const __attribute__((address_space(1))) unsigned int*)g,
        (__attribute__((address_space(3))) unsigned int*)l, 16, 0, 0);
}

// ---------------------------------------------------------------------------
// Batched fp32 -> bf16 weight cast (one launch for all weight tensors)
// ---------------------------------------------------------------------------
#define NSEG 7
struct CastArgs {
    const float* s[NSEG];
    ushort*      d[NSEG];
    int          n4[NSEG];   // quads per segment
    int          total4;
};
__global__ __launch_bounds__(256) void cast_w_kernel(CastArgs a) {
    int idx = blockIdx.x * 256 + threadIdx.x;
    if (idx >= a.total4) return;
    int i = idx, s = 0;
    while (i >= a.n4[s]) { i -= a.n4[s]; ++s; }
    float4 f = ((const float4*)a.s[s])[i];
    ushort4 o;
    o.x = f2b(f.x); o.y = f2b(f.y); o.z = f2b(f.z); o.w = f2b(f.w);
    ((ushort4*)a.d[s])[i] = o;
}

// ---------------------------------------------------------------------------
// Gather 4x4xC patches -> P16[b*S+s][c*16+p*4+q] (bf16) AND write bf16 x into
// cat[:, 0:256] (cat is [32768][512] bf16, second half filled by wm+LN1).
// ---------------------------------------------------------------------------
__global__ __launch_bounds__(256) void gather_kernel(const float* __restrict__ x,
                                                     ushort* __restrict__ P,
                                                     ushort* __restrict__ cat) {
    int bs = blockIdx.x;                 // b*256 + s
    int b = bs >> 8, s = bs & 255;
    int i = s >> 4, j = s & 15;
    int c = threadIdx.x;
    const float* xb = x + (size_t)b * N_ * C_;
    ushort u[16];
#pragma unroll
    for (int pq = 0; pq < 16; ++pq) {
        int p = pq >> 2, q = pq & 3;
        int n = (i * 4 + p) * HH_ + (j * 4 + q);
        float f = xb[(size_t)n * C_ + c];        // coalesced across c
        u[pq] = f2b(f);
        cat[((size_t)(b * N_ + n)) * 512 + c] = u[pq];   // coalesced across c
    }
    ushort* dst = P + (size_t)bs * 4096 + c * 16;
    ((uint4*)dst)[0] = *(uint4*)&u[0];
    ((uint4*)dst)[1] = *(uint4*)&u[8];
}

// ---------------------------------------------------------------------------
// bf16 MFMA GEMM (NT), 128x128 tile, BK=32, 8 waves (512 thr), wave 64x32.
// 2-phase dbuf + read-side XOR swizzle (source col pre-swizzled).
// blockIdx.z = split-K slice (Kchunk each), writes Cf + z*spstride.
// act: 0 none, 1 elu(x)+1, 2 relu, 3 elu+1 if col<256 else none.
// Output: Cb (bf16) if non-null else Cf (fp32).
// ---------------------------------------------------------------------------
__global__ __launch_bounds__(512) void gemm_bf16(
    const ushort* __restrict__ A, int lda,
    const ushort* __restrict__ W, int ldw,
    float* __restrict__ Cf, ushort* __restrict__ Cb, int ldc,
    int Kchunk, int act, long spstride)
{
    __shared__ ushort As[2 * BM * BK];   // 2 x 8 KB
    __shared__ ushort Bs[2 * BN * BK];
    const int t = threadIdx.x;
    const int lane = t & 63;
    const int w = t >> 6;                        // 0..7
    const int wr = w >> 2, wc = w & 3;           // 2 row-groups x 4 col-groups
    const int fr = lane & 15, fq = lane >> 4;
    const int bm = blockIdx.x * BM, bn = blockIdx.y * BN;
    const long koff = (long)blockIdx.z * Kchunk;

    f32x4 acc[4][2] = {};

    const ushort* Ag = A + (size_t)bm * lda + koff;
    const ushort* Wg = W + (size_t)bn * ldw + koff;
    char* AsB = (char*)As;
    char* BsB = (char*)Bs;
    const int wuni = (t & ~63) * 16;

    const int srow = t >> 2;                     // 0..127
    const int skb0 = ((t & 3) * 8) ^ ((srow & 3) * 8);

    auto STAGE = [&](int buf, int k0) {
        gload16(Ag + (size_t)srow * lda + k0 + skb0, AsB + buf * 8192 + wuni);
        gload16(Wg + (size_t)srow * ldw + k0 + skb0, BsB + buf * 8192 + wuni);
    };

    STAGE(0, 0);
    __syncthreads();
    int cur = 0;
    for (int k0 = 0; k0 < Kchunk; k0 += BK) {
        if (k0 + BK < Kchunk) STAGE(cur ^ 1, k0 + BK);

        const ushort* Ac = As + cur * (BM * BK);
        const ushort* Bc = Bs + cur * (BN * BK);
        bf16x8 af[4], bv[2];
#pragma unroll
        for (int m = 0; m < 4; ++m) {
            int ra = wr * 64 + m * 16 + fr;
            af[m] = *(const bf16x8*)&Ac[ra * BK + (fq * 8 ^ ((ra & 3) * 8))];
        }
#pragma unroll
        for (int n = 0; n < 2; ++n) {
            int rb = wc * 32 + n * 16 + fr;
            bv[n] = *(const bf16x8*)&Bc[rb * BK + (fq * 8 ^ ((rb & 3) * 8))];
        }
#pragma unroll
        for (int m = 0; m < 4; ++m)
#pragma unroll
            for (int n = 0; n < 2; ++n)
                acc[m][n] = __builtin_amdgcn_mfma_f32_16x16x32_bf16(
                    af[m], bv[n], acc[m][n], 0, 0, 0);

        __syncthreads();
        cur ^= 1;
    }

    float* Cfz = Cf ? Cf + (size_t)blockIdx.z * spstride : nullptr;
#pragma unroll
    for (int m = 0; m < 4; ++m) {
#pragma unroll
        for (int n = 0; n < 2; ++n) {
            int col = bn + wc * 32 + n * 16 + fr;
#pragma unroll
            for (int i = 0; i < 4; ++i) {
                int row = bm + wr * 64 + m * 16 + fq * 4 + i;
                float v = acc[m][n][i];
                if (act == 1 || (act == 3 && col < 256))
                    v = v > 0.f ? v + 1.f : __expf(v);
                else if (act == 2) v = fmaxf(v, 0.f);
                if (Cb) Cb[(size_t)row * ldc + col] = f2b(v);
                else    Cfz[(size_t)row * ldc + col] = v;
            }
        }
    }
}

// ---------------------------------------------------------------------------
// Wide bf16 MFMA GEMM (NT): BM=64 x BN=256 (full row of an N=256 output),
// 8 waves (2 row-groups x 4 col-groups of 64), BK=32, dbuf + swizzle.
// mode 0: write bf16 (act applied).
// mode 1: LayerNorm epilogue (g,bvec) -> bf16 outb (ld=ldo).
// mode 2: LayerNorm epilogue + fp32 residual -> fp32 outf (ld=256).
// LN: per-row sum/sumsq via 4-step shfl_xor (over fr) + rs[4][64] cross-wave.
// ---------------------------------------------------------------------------
__global__ __launch_bounds__(512) void gemm_wide(
    const ushort* __restrict__ A, int lda,
    const ushort* __restrict__ W, int ldw,
    int K, int act, int mode,
    ushort* __restrict__ outb, int ldo,
    float* __restrict__ outf,
    const float* __restrict__ g, const float* __restrict__ bvec,
    const float* __restrict__ resid)
{
    __shared__ ushort As[2 * 64 * 32];    // 2 x 4 KB
    __shared__ ushort Bs[2 * 256 * 32];   // 2 x 16 KB
    __shared__ float2 rs[4][64];          // LN cross-wave partials
    const int t = threadIdx.x;
    const int lane = t & 63;
    const int w = t >> 6;
    const int wr = w >> 2, wc = w & 3;            // 2 x 4 waves, 32r x 64c each
    const int fr = lane & 15, fq = lane >> 4;
    const int bm = blockIdx.x * 64;

    f32x4 acc[2][4] = {};
    const ushort* Ag = A + (size_t)bm * lda;
    char* AsB = (char*)As;
    char* BsB = (char*)Bs;
    const int wuni = (t & ~63) * 16;

    const int srow = t >> 2;                      // 0..127
    const int skb = ((t & 3) * 8) ^ ((srow & 3) * 8);

    auto STAGE = [&](int buf, int k0) {
        // B: 256 rows x 32k = 16 KB = 1024 chunks: c=t (rows 0..127) and
        // c=512+t (rows 128..255; same row&3 -> same swizzle).
        gload16(W + (size_t)srow * ldw + k0 + skb, BsB + buf * 16384 + wuni);
        gload16(W + (size_t)(128 + srow) * ldw + k0 + skb,
                BsB + buf * 16384 + 8192 + wuni);
        if (t < 256)   // A: 64 rows x 32k = 4 KB (waves 0..3, wave-uniform)
            gload16(Ag + (size_t)srow * lda + k0 + skb, AsB + buf * 4096 + wuni);
    };

    STAGE(0, 0);
    __syncthreads();
    int cur = 0;
    for (int k0 = 0; k0 < K; k0 += BK) {
        if (k0 + BK < K) STAGE(cur ^ 1, k0 + BK);

        const ushort* Ac = As + cur * (64 * 32);
        const ushort* Bc = Bs + cur * (256 * 32);
        bf16x8 af[2], bv[4];
#pragma unroll
        for (int m = 0; m < 2; ++m) {
            int ra = wr * 32 + m * 16 + fr;
            af[m] = *(const bf16x8*)&Ac[ra * 32 + (fq * 8 ^ ((ra & 3) * 8))];
        }
#pragma unroll
        for (int n = 0; n < 4; ++n) {
            int rb = wc * 64 + n * 16 + fr;
            bv[n] = *(const bf16x8*)&Bc[rb * 32 + (fq * 8 ^ ((rb & 3) * 8))];
        }
#pragma unroll
        for (int m = 0; m < 2; ++m)
#pragma unroll
            for (int n = 0; n < 4; ++n)
                acc[m][n] = __builtin_amdgcn_mfma_f32_16x16x32_bf16(
                    af[m], bv[n], acc[m][n], 0, 0, 0);

        __syncthreads();
        cur ^= 1;
    }

    if (mode == 0) {
#pragma unroll
        for (int m = 0; m < 2; ++m)
#pragma unroll
            for (int n = 0; n < 4; ++n) {
                int col = wc * 64 + n * 16 + fr;
#pragma unroll
                for (int i = 0; i < 4; ++i) {
                    int row = bm + wr * 32 + m * 16 + fq * 4 + i;
                    float v = acc[m][n][i];
                    if (act == 1) v = v > 0.f ? v + 1.f : __expf(v);
                    else if (act == 2) v = fmaxf(v, 0.f);
                    outb[(size_t)row * ldo + col] = f2b(v);
                }
            }
        return;
    }

    // ---- LayerNorm epilogue (mode 1/2) ----
#pragma unroll
    for (int m = 0; m < 2; ++m)
#pragma unroll
        for (int i = 0; i < 4; ++i) {
            float s = 0.f, q = 0.f;
#pragma unroll
            for (int n = 0; n < 4; ++n) {
                float v = acc[m][n][i];
                s += v; q += v * v;
            }
#pragma unroll
            for (int msk = 1; msk < 16; msk <<= 1) {
                s += __shfl_xor(s, msk);
                q += __shfl_xor(q, msk);
            }
            if (fr == 0)
                rs[wc][wr * 32 + m * 16 + fq * 4 + i] = make_float2(s, q);
        }
    __syncthreads();
#pragma unroll
    for (int m = 0; m < 2; ++m)
#pragma unroll
        for (int i = 0; i < 4; ++i) {
            int r64 = wr * 32 + m * 16 + fq * 4 + i;
            float S = 0.f, Q = 0.f;
#pragma unroll
            for (int c4 = 0; c4 < 4; ++c4) {
                float2 p = rs[c4][r64];
                S += p.x; Q += p.y;
            }
            float mean = S * (1.f / C_);
            float rstd = rsqrtf(Q * (1.f / C_) - mean * mean + 1e-5f);
            int row = bm + r64;
#pragma unroll
            for (int n = 0; n < 4; ++n) {
                int col = wc * 64 + n * 16 + fr;
                float y = (acc[m][n][i] - mean) * rstd * g[col] + bvec[col];
                if (mode == 1) {
                    outb[(size_t)row * ldo + col] = f2b(y);
                } else {
                    y += resid[(size_t)row * 256 + col];
                    outf[(size_t)row * 256 + col] = y;
                }
            }
        }
}

// ---------------------------------------------------------------------------
// Sum NSLICE split-K partials + conv bias, then LayerNorm -> bf16 src.
// Wave-per-row: 4 rows/block, lane owns 4 cols, shfl_xor reduction.
// ---------------------------------------------------------------------------
__global__ __launch_bounds__(256) void ln_reduce_kernel(
    const float* __restrict__ part,     // [NSLICE][2048][256]
    const float* __restrict__ bias,
    const float* __restrict__ g, const float* __restrict__ bvec,
    ushort* __restrict__ outb)
{
    int row = blockIdx.x * 4 + (threadIdx.x >> 6);
    int lane = threadIdx.x & 63;
    int c0 = lane * 4;
    float4 v = *(const float4*)&bias[c0];
#pragma unroll
    for (int s = 0; s < NSLICE; ++s) {
        float4 p = *(const float4*)&part[(size_t)s * 2048 * 256 + (size_t)row * 256 + c0];
        v.x += p.x; v.y += p.y; v.z += p.z; v.w += p.w;
    }
    float s1 = v.x + v.y + v.z + v.w;
    float s2 = v.x * v.x + v.y * v.y + v.z * v.z + v.w * v.w;
#pragma unroll
    for (int m = 1; m < 64; m <<= 1) {
        s1 += __shfl_xor(s1, m);
        s2 += __shfl_xor(s2, m);
    }
    float mean = s1 * (1.f / C_);
    float rstd = rsqrtf(s2 * (1.f / C_) - mean * mean + 1e-5f);
    float4 gv = *(const float4*)&g[c0];
    float4 bb = *(const float4*)&bvec[c0];
    ushort4 o;
    o.x = f2b((v.x - mean) * rstd * gv.x + bb.x);
    o.y = f2b((v.y - mean) * rstd * gv.y + bb.y);
    o.z = f2b((v.z - mean) * rstd * gv.z + bb.z);
    o.w = f2b((v.w - mean) * rstd * gv.w + bb.w);
    *(ushort4*)&outb[(size_t)row * C_ + c0] = o;
}

// ---------------------------------------------------------------------------
// Per (b,h): KV[d][v] = sum_s K[s,d]*V[s,v];  Ksum[d] = sum_s K[s,d]
// Input: fused kv16 [2048][512] bf16 (cols 0:256 = K heads, 256:512 = V heads)
// ---------------------------------------------------------------------------
__global__ __launch_bounds__(256) void kv_kernel(const ushort* __restrict__ kvin,
                                                 float* __restrict__ KV,
                                                 float* __restrict__ Ksum) {
    int bh = blockIdx.x;
    int b = bh >> 3, h = bh & 7;
    const ushort* Kp = kvin + (size_t)b * S_ * 512 + h * D_;
    const ushort* Vp = Kp + 256;
    int tid = threadIdx.x;
    __shared__ float Ks[8][32], Vs[8][32];
    int d = tid >> 3, vq = tid & 7;
    int ls = tid >> 5, lc = tid & 31;
    float acc[4] = {0.f, 0.f, 0.f, 0.f};
    float ks = 0.f;
    for (int s0 = 0; s0 < S_; s0 += 8) {
        __syncthreads();
        Ks[ls][lc] = b2f(Kp[(size_t)(s0 + ls) * 512 + lc]);
        Vs[ls][lc] = b2f(Vp[(size_t)(s0 + ls) * 512 + lc]);
        __syncthreads();
#pragma unroll
        for (int ss = 0; ss < 8; ++ss) {
            float kd = Ks[ss][d];
            if (vq == 0) ks += kd;
#pragma unroll
            for (int jj = 0; jj < 4; ++jj)
                acc[jj] += kd * Vs[ss][vq * 4 + jj];
        }
    }
    float* kvout = KV + ((size_t)bh * 32 + d) * 32 + vq * 4;
#pragma unroll
    for (int jj = 0; jj < 4; ++jj) kvout[jj] = acc[jj];
    if (vq == 0) Ksum[bh * 32 + d] = ks;
}

// ---------------------------------------------------------------------------
// msg[row, h*32+v] = (Q·KV[h,:,v]) / (Q·Ksum[h] + eps), Q bf16.
// ---------------------------------------------------------------------------
__global__ __launch_bounds__(256) void msg_kernel(const ushort* __restrict__ Q,
                                                  const float* __restrict__ KV,
                                                  const float* __restrict__ Ksum,
                                                  ushort* __restrict__ out) {
    const int row0 = blockIdx.x * 64;
    const int b = row0 >> 12;
    const int tid = threadIdx.x;
    const int h = tid >> 5, v = tid & 31;
    __shared__ float KVs[8192];
    __shared__ float Kss[256];
    __shared__ ushort Qs[8][256];
    const float4* kvsrc = (const float4*)(KV + (size_t)b * 8192);
#pragma unroll
    for (int i = 0; i < 8; ++i)
        ((float4*)KVs)[i * 256 + tid] = kvsrc[i * 256 + tid];
    if (tid < 64)
        ((float4*)Kss)[tid] = ((const float4*)(Ksum + b * 256))[tid];
    __syncthreads();
    float kvr[32], ksr[32];
#pragma unroll
    for (int d = 0; d < 32; ++d) {
        kvr[d] = KVs[h * 1024 + d * 32 + v];
        ksr[d] = Kss[h * 32 + d];
    }
    for (int r0 = 0; r0 < 64; r0 += 8) {
        __syncthreads();
        { int r = tid >> 5, c8 = (tid & 31) * 8;
          *(uint4*)&Qs[r][c8] = *(const uint4*)&Q[(size_t)(row0 + r0 + r) * 256 + c8]; }
        __syncthreads();
#pragma unroll
        for (int r = 0; r < 8; ++r) {
            ushort q[32];
            *(uint4*)&q[0]  = *(const uint4*)&Qs[r][h * 32 + 0];
            *(uint4*)&q[8]  = *(const uint4*)&Qs[r][h * 32 + 8];
            *(uint4*)&q[16] = *(const uint4*)&Qs[r][h * 32 + 16];
            *(uint4*)&q[24] = *(const uint4*)&Qs[r][h * 32 + 24];
            float z = 1e-6f, m = 0.f;
#pragma unroll
            for (int d = 0; d < 32; ++d) {
                float qd = b2f(q[d]);
                z = fmaf(qd, ksr[d], z);
                m = fmaf(qd, kvr[d], m);
            }
            out[(size_t)(row0 + r0 + r) * 256 + tid] = f2b(m / z);
        }
    }
}

// ---------------------------------------------------------------------------
extern "C" void kernel_launch(void* const* d_in, const int* in_sizes, int n_in,
                              void* d_out, int out_size, void* d_ws, size_t ws_size,
                              hipStream_t stream) {
    const float* x      = (const float*)d_in[0];
    const float* sr_w   = (const float*)d_in[1];   // [256,4096] OIHW flat
    const float* sr_b   = (const float*)d_in[2];
    const float* norm_g = (const float*)d_in[3];
    const float* norm_b = (const float*)d_in[4];
    const float* wq     = (const float*)d_in[5];
    const float* wk     = (const float*)d_in[6];
    const float* wv     = (const float*)d_in[7];
    const float* wm     = (const float*)d_in[8];
    const float* w1     = (const float*)d_in[9];   // [512,512]
    const float* w2     = (const float*)d_in[10];  // [256,512]
    const float* n1g    = (const float*)d_in[11];
    const float* n1b    = (const float*)d_in[12];
    const float* n2g    = (const float*)d_in[13];
    const float* n2b    = (const float*)d_in[14];
    float* out = (float*)d_out;

    char* base = (char*)d_ws;
    size_t off = 0;
    auto alloc = [&](size_t bytes) {
        char* p = base + off;
        off += (bytes + 1023) & ~(size_t)1023;
        return p;
    };
    ushort* P16      = (ushort*)alloc(2048ull * 4096 * 2);               // 16.8 MB
    float*  partial  = (float*) alloc((size_t)NSLICE * 2048 * 256 * 4);  // 33.6 MB
    ushort* cat      = (ushort*)alloc(32768ull * 512 * 2);               // 33.6 MB
    ushort* src16    = (ushort*)alloc(2048ull * 256 * 2);
    ushort* kv16     = (ushort*)alloc(2048ull * 512 * 2);                // 2.1 MB
    ushort* h1_16    = (ushort*)alloc(32768ull * 512 * 2);               // 33.6 MB
    float*  KV       = (float*) alloc(64ull * 32 * 32 * 4);
    float*  Ksum     = (float*) alloc(64ull * 32 * 4);
    ushort* srw16    = (ushort*)alloc(1048576ull * 2);
    ushort* wq16     = (ushort*)alloc(65536ull * 2);
    ushort* wkv16    = (ushort*)alloc(131072ull * 2);                    // [wk;wv]
    ushort* wm16     = (ushort*)alloc(65536ull * 2);
    ushort* w1_16    = (ushort*)alloc(262144ull * 2);
    ushort* w2_16    = (ushort*)alloc(131072ull * 2);
    // lifetime-based aliasing:
    ushort* qbuf16 = (ushort*)partial;   // partial dead after ln_reduce
    ushort* msg16  = P16;                // P16 dead after conv GEMM

    // 0. cast all weights to bf16 in one launch (wk,wv -> stacked wkv16)
    CastArgs ca;
    ca.s[0] = sr_w; ca.d[0] = srw16;         ca.n4[0] = 1048576 / 4;
    ca.s[1] = wq;   ca.d[1] = wq16;          ca.n4[1] = 65536 / 4;
    ca.s[2] = wk;   ca.d[2] = wkv16;         ca.n4[2] = 65536 / 4;
    ca.s[3] = wv;   ca.d[3] = wkv16 + 65536; ca.n4[3] = 65536 / 4;
    ca.s[4] = wm;   ca.d[4] = wm16;          ca.n4[4] = 65536 / 4;
    ca.s[5] = w1;   ca.d[5] = w1_16;         ca.n4[5] = 262144 / 4;
    ca.s[6] = w2;   ca.d[6] = w2_16;         ca.n4[6] = 131072 / 4;
    ca.total4 = (1048576 + 4 * 65536 + 262144 + 131072) / 4;
    cast_w_kernel<<<(ca.total4 + 255) / 256, 256, 0, stream>>>(ca);

    // 1. patch gather (bf16) + bf16 x into cat[:, 0:256]
    gather_kernel<<<2048, 256, 0, stream>>>(x, P16, cat);

    // 2. subsample conv GEMM, split-K=16 -> partials; fused reduce+bias+LN -> src16
    { dim3 g(2048 / BM, 256 / BN, NSLICE);
      gemm_bf16<<<g, 512, 0, stream>>>(P16, 4096, srw16, 4096,
                                       partial, nullptr, 256, 4096 / NSLICE, 0, 2048l * 256); }
    ln_reduce_kernel<<<512, 256, 0, stream>>>(partial, sr_b, norm_g, norm_b, src16);

    // 3. fused K|V projection (N=512, act=3), Q projection (wide, elu+1)
    { dim3 g(2048 / BM, 512 / BN);
      gemm_bf16<<<g, 512, 0, stream>>>(src16, 256, wkv16, 256, nullptr, kv16, 512, 256, 3, 0); }
    gemm_wide<<<512, 512, 0, stream>>>(cat, 512, wq16, 256, 256, 1, 0,
                                       qbuf16, 256, nullptr, nullptr, nullptr, nullptr);

    // 4. linear attention
    kv_kernel<<<64, 256, 0, stream>>>(kv16, KV, Ksum);
    msg_kernel<<<512, 256, 0, stream>>>(qbuf16, KV, Ksum, msg16);

    // 5. merge proj + fused LN(norm1) -> bf16 into cat[:, 256:512]
    gemm_wide<<<512, 512, 0, stream>>>(msg16, 256, wm16, 256, 256, 0, 1,
                                       cat + 256, 512, nullptr, n1g, n1b, nullptr);

    // 6. concat-MLP: K=512 GEMM (relu, bf16 out), then w2 GEMM + fused LN2 + residual
    { dim3 g(32768 / BM, 512 / BN);
      gemm_bf16<<<g, 512, 0, stream>>>(cat, 512, w1_16, 512, nullptr, h1_16, 512, 512, 2, 0); }
    gemm_wide<<<512, 512, 0, stream>>>(h1_16, 512, w2_16, 512, 512, 0, 2,
                                       nullptr, 0, out, n2g, n2b, x);
}